// Round 11
// baseline (269.731 us; speedup 1.0000x reference)
//
#include <hip/hip_runtime.h>
#include <math.h>

constexpr int NN   = 50000;   // nodes
constexpr int NE   = 400000;  // edges
constexpr int NR   = 500;     // relations
constexpr int INF_ = 128;     // input feat
constexpr int HIDC = 64;      // layer1 per-head channels
constexpr int NH   = 4;       // heads
constexpr int OUTC = 128;     // layer2 per-head channels
constexpr int MPAD = 50048;   // 391 * 128

typedef __attribute__((ext_vector_type(2))) _Float16 h2;
typedef __attribute__((ext_vector_type(4))) _Float16 h4;
typedef __attribute__((ext_vector_type(8))) _Float16 h8;
typedef __attribute__((ext_vector_type(4))) float f32x4;

__device__ __forceinline__ h2 b2(float f) {
    _Float16 h = (_Float16)f;
    return (h2){h, h};
}

__device__ __forceinline__ h2 lrelu2(h2 x) {
    h2 t = x * (h2){(_Float16)0.2f, (_Float16)0.2f};
#if __has_builtin(__builtin_elementwise_max)
    return __builtin_elementwise_max(x, t);
#else
    h2 r;
    r[0] = x[0] > t[0] ? x[0] : t[0];
    r[1] = x[1] > t[1] ? x[1] : t[1];
    return r;
#endif
}

__device__ __forceinline__ float fdot2a(h2 a, h2 b, float c) {
#if __has_builtin(__builtin_amdgcn_fdot2)
    return __builtin_amdgcn_fdot2(a, b, c, false);
#else
    return c + (float)a[0] * (float)b[0] + (float)a[1] * (float)b[1];
#endif
}

template <int NP>
__device__ __forceinline__ void load_h(const _Float16* p, h2* d) {
    if constexpr (NP == 2) {
        h4 t = *(const h4*)p;
        d[0] = (h2){t[0], t[1]}; d[1] = (h2){t[2], t[3]};
    } else {
        h8 t = *(const h8*)p;
        d[0] = (h2){t[0], t[1]}; d[1] = (h2){t[2], t[3]};
        d[2] = (h2){t[4], t[5]}; d[3] = (h2){t[6], t[7]};
    }
}

__device__ __forceinline__ void gl2lds16(const void* g, void* l) {
    __builtin_amdgcn_global_load_lds(
        (const __attribute__((address_space(1))) unsigned int*)g,
        (__attribute__((address_space(3))) unsigned int*)l, 16, 0, 0);
}

// ---------------- MFMA f16 GEMM, 3-buffer 2-ahead pipeline ----------------
// C = A[* x K](f16) @ Bt[N x K](f16)^T + bias[N]
// If C1 != nullptr: split output at N/2 -> C0[r][c] (c<N/2), C1[r][c-N/2].
// 128x128 tile, BK=32, 4 waves, global_load_lds, XOR swizzle (<=2-way = free).
// 2-ahead staging: tiles t+1, t+2 in flight across barriers (vmcnt(8) steady),
// addressing short-K load latency. Bijective XCD-chunked block swizzle.
// Epilogue: C-tile staged in LDS (pitch 144) -> coalesced 16B/lane stores.
__global__ __launch_bounds__(256) void gemm_mfma(
    const _Float16* __restrict__ A,
    const _Float16* __restrict__ Bt,
    const float* __restrict__ bias,
    _Float16* __restrict__ C0, _Float16* __restrict__ C1,
    int M, int N, int K, int ntn)
{
    __shared__ __align__(16) char smem[49152];           // 3x(As+Bs) 8KB each
    _Float16* As = (_Float16*)smem;                      // [3][4096]
    _Float16* Bs = (_Float16*)(smem + 24576);            // [3][4096]
    const int tid  = threadIdx.x;
    const int lane = tid & 63;
    const int wave = tid >> 6;

    // bijective XCD-chunked swizzle (m204)
    const int nwg = gridDim.x;
    const int q = nwg >> 3, r = nwg & 7;
    const int xcd = blockIdx.x & 7, jj = blockIdx.x >> 3;
    const int swid = (xcd < r ? xcd * (q + 1) : r * (q + 1) + (xcd - r) * q) + jj;
    const int brow = (swid / ntn) * 128;
    const int bcol = (swid % ntn) * 128;

    f32x4 acc[4][4] = {};
    const int wr = (wave >> 1) * 64;
    const int wc = (wave & 1) * 64;
    const int swz = (lane >> 4) ^ ((lane >> 1) & 3);   // read-side swizzled k-chunk

    const int s0 = wave * 64 + lane;
    const int s1 = 256 + wave * 64 + lane;
    const int row0 = s0 >> 2, kc0 = (s0 & 3) ^ ((s0 >> 3) & 3);
    const int row1 = s1 >> 2, kc1 = (s1 & 3) ^ ((s1 >> 3) & 3);
    const _Float16* a0 = A + (size_t)(brow + row0) * K + kc0 * 8;
    const _Float16* a1 = A + (size_t)(brow + row1) * K + kc1 * 8;
    const _Float16* b0 = Bt + (size_t)(bcol + row0) * K + kc0 * 8;
    const _Float16* b1 = Bt + (size_t)(bcol + row1) * K + kc1 * 8;

#define STAGE(buf, k0) do {                                          \
        gl2lds16(a0 + (k0), &As[(buf) * 4096 + wave * 512]);         \
        gl2lds16(b0 + (k0), &Bs[(buf) * 4096 + wave * 512]);         \
        gl2lds16(a1 + (k0), &As[(buf) * 4096 + 2048 + wave * 512]);  \
        gl2lds16(b1 + (k0), &Bs[(buf) * 4096 + 2048 + wave * 512]);  \
    } while (0)

    const int nt = K >> 5;            // >= 4 for all our shapes
    STAGE(0, 0);
    STAGE(1, 32);
    for (int t = 0; t < nt; ++t) {
        if (t + 2 < nt) {
            STAGE((t + 2) % 3, (t + 2) * 32);
            asm volatile("s_waitcnt vmcnt(8)" ::: "memory");  // tile t landed; t+1,t+2 in flight
        } else if (t + 1 < nt) {
            asm volatile("s_waitcnt vmcnt(4)" ::: "memory");
        } else {
            asm volatile("s_waitcnt vmcnt(0)" ::: "memory");
        }
        __builtin_amdgcn_s_barrier();
        __builtin_amdgcn_sched_barrier(0);
        const int cur = t % 3;
        h8 af[4], bfr[4];
        #pragma unroll
        for (int m = 0; m < 4; ++m)
            af[m] = *(const h8*)&As[cur * 4096 + (wr + m * 16 + (lane & 15)) * 32 + swz * 8];
        #pragma unroll
        for (int n = 0; n < 4; ++n)
            bfr[n] = *(const h8*)&Bs[cur * 4096 + (wc + n * 16 + (lane & 15)) * 32 + swz * 8];
        #pragma unroll
        for (int m = 0; m < 4; ++m)
            #pragma unroll
            for (int n = 0; n < 4; ++n)
                acc[m][n] = __builtin_amdgcn_mfma_f32_16x16x32_f16(
                    af[m], bfr[n], acc[m][n], 0, 0, 0);
        __builtin_amdgcn_s_barrier();   // buf[cur] free for overwrite next iter
    }
#undef STAGE

    // ---- epilogue: acc -> LDS (pitch 144) -> coalesced 16B stores ----
    __syncthreads();                     // all waves done with As/Bs reads
    _Float16* Cs = (_Float16*)smem;      // 128 x 144 f16 tile (36864B <= 49152)
    #pragma unroll
    for (int m = 0; m < 4; ++m) {
        int rl0 = wr + m * 16 + (lane >> 4) * 4;
        #pragma unroll
        for (int n = 0; n < 4; ++n) {
            int cl = wc + n * 16 + (lane & 15);
            float bv = bias ? bias[bcol + cl] : 0.f;
            #pragma unroll
            for (int j = 0; j < 4; ++j)
                Cs[(rl0 + j) * 144 + cl] = (_Float16)(acc[m][n][j] + bv);
        }
    }
    __syncthreads();

    const int half = N >> 1;
    const int c8 = (tid & 15) * 8;       // local col of this thread's 16B chunk
    #pragma unroll
    for (int p = 0; p < 8; ++p) {
        int rl = p * 16 + (tid >> 4);
        int rr = brow + rl;
        if (rr >= M) continue;
        h8 vv = *(const h8*)&Cs[rl * 144 + c8];
        int c = bcol + c8;
        if (C1) {
            if (c < half) *(h8*)&C0[(size_t)rr * half + c] = vv;
            else          *(h8*)&C1[(size_t)rr * half + (c - half)] = vv;
        } else {
            *(h8*)&C0[(size_t)rr * N + c] = vv;
        }
    }
}

// ---------------- one-shot prep: converts, transposes, pads, bias packing ----
__global__ __launch_bounds__(256) void prep_all(
    const float* __restrict__ x,
    const float* __restrict__ Wl1, const float* __restrict__ Wr1,
    const float* __restrict__ Wl2, const float* __restrict__ Wr2,
    const float* __restrict__ We1, const float* __restrict__ We2,
    const float* __restrict__ relations,
    const float* __restrict__ bl1, const float* __restrict__ br1,
    const float* __restrict__ bl2, const float* __restrict__ br2,
    _Float16* __restrict__ xh, _Float16* __restrict__ hh,
    _Float16* __restrict__ Bt1, _Float16* __restrict__ Bt2,
    _Float16* __restrict__ BtE, _Float16* __restrict__ relh,
    float* __restrict__ pb1, float* __restrict__ pb2)
{
    constexpr long SXV   = (long)NN * INF_ / 4;
    constexpr long nXP   = (long)(MPAD - NN) * 128;
    constexpr long nHP   = (long)(MPAD - NN) * 256;
    constexpr long nW1   = 128 * 256;
    constexpr long nW2   = 256 * 512;
    constexpr long nWe1  = 128 * 256;
    constexpr long nWe2  = 128 * 512;
    constexpr long nRel  = (long)NR * 128;
    constexpr long nRelP = (512 - NR) * 128;
    constexpr long TOT = SXV + nXP + nHP + 2 * nW1 + 2 * nW2 + nWe1 + nWe2
                       + nRel + nRelP + 512 + 1024;

    for (long i = (long)blockIdx.x * 256 + threadIdx.x; i < TOT;
         i += (long)gridDim.x * 256) {
        long j = i;
        if (j < SXV) {
            float4 v = ((const float4*)x)[j];
            h4 o = {(_Float16)v.x, (_Float16)v.y, (_Float16)v.z, (_Float16)v.w};
            ((h4*)xh)[j] = o;
            continue;
        }
        j -= SXV;
        if (j < nXP) { xh[(long)NN * 128 + j] = (_Float16)0.f; continue; }
        j -= nXP;
        if (j < nHP) { hh[(long)NN * 256 + j] = (_Float16)0.f; continue; }
        j -= nHP;
        if (j < nW1) { long k = j >> 8, n = j & 255; Bt1[n * 128 + k] = (_Float16)Wl1[j]; continue; }
        j -= nW1;
        if (j < nW1) { long k = j >> 8, n = j & 255; Bt1[(256 + n) * 128 + k] = (_Float16)Wr1[j]; continue; }
        j -= nW1;
        if (j < nW2) { long k = j >> 9, n = j & 511; Bt2[n * 256 + k] = (_Float16)Wl2[j]; continue; }
        j -= nW2;
        if (j < nW2) { long k = j >> 9, n = j & 511; Bt2[(512 + n) * 256 + k] = (_Float16)Wr2[j]; continue; }
        j -= nW2;
        if (j < nWe1) { long k = j >> 8, n = j & 255; BtE[n * 128 + k] = (_Float16)We1[j]; continue; }
        j -= nWe1;
        if (j < nWe2) { long k = j >> 9, n = j & 511; BtE[(256 + n) * 128 + k] = (_Float16)We2[j]; continue; }
        j -= nWe2;
        if (j < nRel) { relh[j] = (_Float16)relations[j]; continue; }
        j -= nRel;
        if (j < nRelP) { relh[nRel + j] = (_Float16)0.f; continue; }
        j -= nRelP;
        if (j < 512) { pb1[j] = (j < 256) ? bl1[j] : br1[j - 256]; continue; }
        j -= 512;
        pb2[j] = (j < 512) ? bl2[j] : br2[j - 512];
    }
}

// ---------------- CSR build ----------------
__global__ void count_deg(const int* __restrict__ dst, int* __restrict__ deg, int E)
{
    int i = blockIdx.x * blockDim.x + threadIdx.x;
    if (i < E) atomicAdd(&deg[dst[i]], 1);
}

__global__ __launch_bounds__(256) void scan_block_sums(
    const int* __restrict__ deg, int* __restrict__ bsum, int n)
{
    __shared__ int s[256];
    int i = blockIdx.x * 256 + threadIdx.x;
    s[threadIdx.x] = (i < n) ? deg[i] : 0;
    __syncthreads();
    for (int o = 128; o > 0; o >>= 1) {
        if (threadIdx.x < o) s[threadIdx.x] += s[threadIdx.x + o];
        __syncthreads();
    }
    if (threadIdx.x == 0) bsum[blockIdx.x] = s[0];
}

__global__ __launch_bounds__(256) void scan_bsums(
    const int* __restrict__ bsum, int* __restrict__ boff, int nb)
{
    __shared__ int s[256];
    int v = (threadIdx.x < nb) ? bsum[threadIdx.x] : 0;
    s[threadIdx.x] = v;
    __syncthreads();
    for (int o = 1; o < 256; o <<= 1) {
        int t = (threadIdx.x >= o) ? s[threadIdx.x - o] : 0;
        __syncthreads();
        s[threadIdx.x] += t;
        __syncthreads();
    }
    if (threadIdx.x < nb) boff[threadIdx.x] = s[threadIdx.x] - v; // exclusive
}

__global__ __launch_bounds__(256) void scan_final(
    const int* __restrict__ deg, const int* __restrict__ boff,
    int* __restrict__ offsets, int n)
{
    __shared__ int s[256];
    int i = blockIdx.x * 256 + threadIdx.x;
    int v = (i < n) ? deg[i] : 0;
    s[threadIdx.x] = v;
    __syncthreads();
    for (int o = 1; o < 256; o <<= 1) {
        int t = (threadIdx.x >= o) ? s[threadIdx.x - o] : 0;
        __syncthreads();
        s[threadIdx.x] += t;
        __syncthreads();
    }
    int incl = s[threadIdx.x];
    int excl = incl - v;
    if (i < n) offsets[i] = boff[blockIdx.x] + excl;
    if (i == n - 1) offsets[n] = boff[blockIdx.x] + incl;
}

__global__ void fill_adj(const int* __restrict__ src, const int* __restrict__ rel,
                         const int* __restrict__ dst, const int* __restrict__ offsets,
                         int* __restrict__ cursor,
                         int* __restrict__ adj_src, int* __restrict__ adj_rel, int E)
{
    int e = blockIdx.x * blockDim.x + threadIdx.x;
    if (e < E) {
        int d = dst[e];
        int p = atomicAdd(&cursor[d], 1);
        int slot = offsets[d] + p;
        adj_src[slot] = src[e];
        adj_rel[slot] = rel[e];
    }
}

// ---------------- fused per-node GATv2 attention (2 waves per block) --------
template <int CPH, bool CONCAT>
__global__ __launch_bounds__(128) void gat_node(
    const _Float16* __restrict__ xl,    // [n][HC] source-transform rows (gathered)
    const _Float16* __restrict__ xr,    // [n][HC] dest-transform rows
    const _Float16* __restrict__ erel,  // [NR rows][ldE] relations@We slice
    int ldE,
    const int* __restrict__ adj_src, const int* __restrict__ adj_rel,
    const int* __restrict__ offsets,
    const float* __restrict__ att,      // [HC] f32
    const float* __restrict__ bias,     // CONCAT ? [HC] : [CPH]
    void* __restrict__ out, int n)
{
    constexpr int HC  = NH * CPH;
    constexpr int VPL = HC / 64;
    constexpr int NP  = VPL / 2;
    const int lane = threadIdx.x & 63;
    const int v = blockIdx.x * 2 + (threadIdx.x >> 6);
    if (v >= n) return;
    const int loff = lane * VPL;

    h2 xlv[NP], xrv[NP], attp[NP], acc[NP];
    load_h<NP>(xl + (size_t)v * HC + loff, xlv);
    load_h<NP>(xr + (size_t)v * HC + loff, xrv);
    #pragma unroll
    for (int p = 0; p < NP; ++p) {
        attp[p][0] = (_Float16)att[loff + 2 * p];
        attp[p][1] = (_Float16)att[loff + 2 * p + 1];
        acc[p] = xlv[p];
    }

    // self loop logit
    float pS = 0.f;
    #pragma unroll
    for (int p = 0; p < NP; ++p) pS = fdot2a(lrelu2(xlv[p] + xrv[p]), attp[p], pS);
    pS += __shfl_xor(pS, 1);
    pS += __shfl_xor(pS, 2);
    pS += __shfl_xor(pS, 4);
    pS += __shfl_xor(pS, 8);
    float m_run = pS, l_run = 1.f;

    const int beg = offsets[v], end = offsets[v + 1];
    int idx = beg;
    for (; idx + 4 <= end; idx += 4) {
        int s0 = adj_src[idx],     s1 = adj_src[idx + 1];
        int s2 = adj_src[idx + 2], s3 = adj_src[idx + 3];
        int r0 = adj_rel[idx],     r1 = adj_rel[idx + 1];
        int r2 = adj_rel[idx + 2], r3 = adj_rel[idx + 3];
        h2 xs0[NP], xs1[NP], xs2[NP], xs3[NP];
        h2 e0[NP], e1[NP], e2[NP], e3[NP];
        load_h<NP>(xl + (size_t)s0 * HC + loff, xs0);
        load_h<NP>(xl + (size_t)s1 * HC + loff, xs1);
        load_h<NP>(xl + (size_t)s2 * HC + loff, xs2);
        load_h<NP>(xl + (size_t)s3 * HC + loff, xs3);
        load_h<NP>(erel + (size_t)r0 * ldE + loff, e0);
        load_h<NP>(erel + (size_t)r1 * ldE + loff, e1);
        load_h<NP>(erel + (size_t)r2 * ldE + loff, e2);
        load_h<NP>(erel + (size_t)r3 * ldE + loff, e3);
        float p0 = 0.f, p1 = 0.f, p2 = 0.f, p3 = 0.f;
        #pragma unroll
        for (int p = 0; p < NP; ++p) {
            p0 = fdot2a(lrelu2(xs0[p] + xrv[p] + e0[p]), attp[p], p0);
            p1 = fdot2a(lrelu2(xs1[p] + xrv[p] + e1[p]), attp[p], p1);
            p2 = fdot2a(lrelu2(xs2[p] + xrv[p] + e2[p]), attp[p], p2);
            p3 = fdot2a(lrelu2(xs3[p] + xrv[p] + e3[p]), attp[p], p3);
        }
        p0 += __shfl_xor(p0, 1); p1 += __shfl_xor(p1, 1);
        p2 += __shfl_xor(p2, 1); p3 += __shfl_xor(p3, 1);
        p0 += __shfl_xor(p0, 2); p1 += __shfl_xor(p1, 2);
        p2 += __shfl_xor(p2, 2); p3 += __shfl_xor(p3, 2);
        p0 += __shfl_xor(p0, 4); p1 += __shfl_xor(p1, 4);
        p2 += __shfl_xor(p2, 4); p3 += __shfl_xor(p3, 4);
        p0 += __shfl_xor(p0, 8); p1 += __shfl_xor(p1, 8);
        p2 += __shfl_xor(p2, 8); p3 += __shfl_xor(p3, 8);
        float mx = fmaxf(fmaxf(fmaxf(p0, p1), fmaxf(p2, p3)), m_run);
        float sc = __expf(m_run - mx);
        float w0 = __expf(p0 - mx), w1 = __expf(p1 - mx);
        float w2 = __expf(p2 - mx), w3 = __expf(p3 - mx);
        l_run = l_run * sc + ((w0 + w1) + (w2 + w3));
        h2 sc2 = b2(sc), w02 = b2(w0), w12 = b2(w1), w22 = b2(w2), w32 = b2(w3);
        #pragma unroll
        for (int p = 0; p < NP; ++p)
            acc[p] = ((acc[p] * sc2 + xs0[p] * w02) + (xs1[p] * w12 + xs2[p] * w22))
                   + xs3[p] * w32;
        m_run = mx;
    }
    for (; idx < end; ++idx) {
        int s0 = adj_src[idx], r0 = adj_rel[idx];
        h2 xs0[NP], e0[NP];
        load_h<NP>(xl + (size_t)s0 * HC + loff, xs0);
        load_h<NP>(erel + (size_t)r0 * ldE + loff, e0);
        float p0 = 0.f;
        #pragma unroll
        for (int p = 0; p < NP; ++p)
            p0 = fdot2a(lrelu2(xs0[p] + xrv[p] + e0[p]), attp[p], p0);
        p0 += __shfl_xor(p0, 1);
        p0 += __shfl_xor(p0, 2);
        p0 += __shfl_xor(p0, 4);
        p0 += __shfl_xor(p0, 8);
        float mx = fmaxf(m_run, p0);
        float sc = __expf(m_run - mx);
        float w0 = __expf(p0 - mx);
        l_run = l_run * sc + w0;
        h2 sc2 = b2(sc), w02 = b2(w0);
        #pragma unroll
        for (int p = 0; p < NP; ++p) acc[p] = acc[p] * sc2 + xs0[p] * w02;
        m_run = mx;
    }

    float inv = 1.f / l_run;
    if constexpr (CONCAT) {
        _Float16* ob = (_Float16*)out + (size_t)v * HC + loff;
        if constexpr (NP == 2) {
            h4 o;
            #pragma unroll
            for (int p = 0; p < NP; ++p) {
                o[2 * p]     = (_Float16)((float)acc[p][0] * inv + bias[loff + 2 * p]);
                o[2 * p + 1] = (_Float16)((float)acc[p][1] * inv + bias[loff + 2 * p + 1]);
            }
            *(h4*)ob = o;
        } else {
            h8 o;
            #pragma unroll
            for (int p = 0; p < NP; ++p) {
                o[2 * p]     = (_Float16)((float)acc[p][0] * inv + bias[loff + 2 * p]);
                o[2 * p + 1] = (_Float16)((float)acc[p][1] * inv + bias[loff + 2 * p + 1]);
            }
            *(h8*)ob = o;
        }
    } else {
        float* of = (float*)out;
        float t[VPL];
        #pragma unroll
        for (int j = 0; j < VPL; ++j) {
            t[j] = (float)acc[j / 2][j & 1] * inv;
            t[j] += __shfl_xor(t[j], 16);
            t[j] += __shfl_xor(t[j], 32);
        }
        if (lane < 16) {
            #pragma unroll
            for (int j = 0; j < VPL; ++j)
                of[(size_t)v * CPH + lane * VPL + j] = 0.25f * t[j] + bias[lane * VPL + j];
        }
    }
}

// ---------------- host launcher ----------------
extern "C" void kernel_launch(void* const* d_in, const int* in_sizes, int n_in,
                              void* d_out, int out_size, void* d_ws, size_t ws_size,
                              hipStream_t stream)
{
    const float* x         = (const float*)d_in[0];
    const int*   ei        = (const int*)d_in[1];
    const float* relations = (const float*)d_in[2];
    const float* Wl1  = (const float*)d_in[3];
    const float* bl1  = (const float*)d_in[4];
    const float* Wr1  = (const float*)d_in[5];
    const float* br1  = (const float*)d_in[6];
    const float* We1  = (const float*)d_in[7];
    const float* att1 = (const float*)d_in[8];
    const float* bias1= (const float*)d_in[9];
    const float* Wl2  = (const float*)d_in[10];
    const float* bl2  = (const float*)d_in[11];
    const float* Wr2  = (const float*)d_in[12];
    const float* br2  = (const float*)d_in[13];
    const float* We2  = (const float*)d_in[14];
    const float* att2 = (const float*)d_in[15];
    const float* bias2= (const float*)d_in[16];
    float* out = (float*)d_out;

    const int* src = ei;
    const int* rel = ei + NE;
    const int* dst = ei + 2 * NE;

    // ---- workspace layout (f16 = _Float16) ----
    _Float16* xh   = (_Float16*)d_ws;                  // MPAD*128
    _Float16* hh   = xh + (size_t)MPAD * 128;          // MPAD*256
    _Float16* xl1  = hh + (size_t)MPAD * 256;          // NN*256
    _Float16* xr1  = xl1 + (size_t)NN * 256;           // NN*256
    _Float16* xl2  = xr1 + (size_t)NN * 256;           // NN*512
    _Float16* xr2  = xl2 + (size_t)NN * 512;           // NN*512
    _Float16* Bt1  = xr2 + (size_t)NN * 512;           // 512*128
    _Float16* Bt2  = Bt1 + 512 * 128;                  // 1024*256
    _Float16* BtE  = Bt2 + 1024 * 256;                 // 768*128
    _Float16* relh = BtE + 768 * 128;                  // 512*128
    _Float16* erelC= relh + 512 * 128;                 // 512*768 (500 used)
    float* pb1     = (float*)(erelC + 512 * 768);      // 512
    float* pb2     = pb1 + 512;                        // 1024
    int* deg     = (int*)(pb2 + 1024);
    int* cursor  = deg + NN;
    int* offsets = cursor + NN;       // NN+1
    int* bsum    = offsets + NN + 1;  // 256
    int* boff    = bsum + 256;        // 256
    int* adj_src = boff + 256;        // NE
    int* adj_rel = adj_src + NE;      // NE

    const int NB = (NN + 255) / 256;  // 196
    const int EB = (NE + 255) / 256;

    // --- zero deg+cursor (adjacent) ---
    hipMemsetAsync(deg, 0, (size_t)2 * NN * sizeof(int), stream);

    // --- one-shot prep (converts/transposes/pads/bias packing) ---
    prep_all<<<2048, 256, 0, stream>>>(x, Wl1, Wr1, Wl2, Wr2, We1, We2, relations,
                                       bl1, br1, bl2, br2,
                                       xh, hh, Bt1, Bt2, BtE, relh, pb1, pb2);

    // --- CSR by destination ---
    count_deg<<<EB, 256, 0, stream>>>(dst, deg, NE);
    scan_block_sums<<<NB, 256, 0, stream>>>(deg, bsum, NN);
    scan_bsums<<<1, 256, 0, stream>>>(bsum, boff, NB);
    scan_final<<<NB, 256, 0, stream>>>(deg, boff, offsets, NN);
    fill_adj<<<EB, 256, 0, stream>>>(src, rel, dst, offsets, cursor, adj_src, adj_rel, NE);

    // --- relation tables: erelC[500 x 768] = relations @ [We1 | We2] ---
    gemm_mfma<<<4 * 6, 256, 0, stream>>>(relh, BtE, nullptr, erelC, nullptr,
                                         NR, 768, 128, 6);

    // --- layer 1 transform: xl1 = x@Wl1+bl1, xr1 = x@Wr1+br1 (one GEMM) ---
    gemm_mfma<<<(MPAD / 128) * 4, 256, 0, stream>>>(xh, Bt1, pb1, xl1, xr1,
                                                    NN, 512, 128, 4);

    // --- layer 1 attention -> h (f16); 2 waves per block ---
    gat_node<HIDC, true><<<(NN + 1) / 2, 128, 0, stream>>>(
        xl1, xr1, erelC, 768, adj_src, adj_rel, offsets, att1, bias1, hh, NN);

    // --- layer 2 transform: xl2 = h@Wl2+bl2, xr2 = h@Wr2+br2 ---
    gemm_mfma<<<(MPAD / 128) * 8, 256, 0, stream>>>(hh, Bt2, pb2, xl2, xr2,
                                                    NN, 1024, 256, 8);

    // --- layer 2 attention (mean over heads) -> out ---
    gat_node<OUTC, false><<<(NN + 1) / 2, 128, 0, stream>>>(
        xl2, xr2, erelC + 256, 768, adj_src, adj_rel, offsets, att2, bias2, out, NN);
}

// Round 12
// 256.992 us; speedup vs baseline: 1.0496x; 1.0496x over previous
//
#include <hip/hip_runtime.h>
#include <math.h>

constexpr int NN   = 50000;   // nodes
constexpr int NE   = 400000;  // edges
constexpr int NR   = 500;     // relations
constexpr int INF_ = 128;     // input feat
constexpr int HIDC = 64;      // layer1 per-head channels
constexpr int NH   = 4;       // heads
constexpr int OUTC = 128;     // layer2 per-head channels
constexpr int MPAD = 50048;   // 391 * 128

typedef __attribute__((ext_vector_type(2))) _Float16 h2;
typedef __attribute__((ext_vector_type(4))) _Float16 h4;
typedef __attribute__((ext_vector_type(8))) _Float16 h8;
typedef __attribute__((ext_vector_type(4))) float f32x4;

__device__ __forceinline__ h2 b2(float f) {
    _Float16 h = (_Float16)f;
    return (h2){h, h};
}

__device__ __forceinline__ h2 lrelu2(h2 x) {
    h2 t = x * (h2){(_Float16)0.2f, (_Float16)0.2f};
#if __has_builtin(__builtin_elementwise_max)
    return __builtin_elementwise_max(x, t);
#else
    h2 r;
    r[0] = x[0] > t[0] ? x[0] : t[0];
    r[1] = x[1] > t[1] ? x[1] : t[1];
    return r;
#endif
}

__device__ __forceinline__ float fdot2a(h2 a, h2 b, float c) {
#if __has_builtin(__builtin_amdgcn_fdot2)
    return __builtin_amdgcn_fdot2(a, b, c, false);
#else
    return c + (float)a[0] * (float)b[0] + (float)a[1] * (float)b[1];
#endif
}

template <int NP>
__device__ __forceinline__ void load_h(const _Float16* p, h2* d) {
    if constexpr (NP == 2) {
        h4 t = *(const h4*)p;
        d[0] = (h2){t[0], t[1]}; d[1] = (h2){t[2], t[3]};
    } else {
        h8 t = *(const h8*)p;
        d[0] = (h2){t[0], t[1]}; d[1] = (h2){t[2], t[3]};
        d[2] = (h2){t[4], t[5]}; d[3] = (h2){t[6], t[7]};
    }
}

__device__ __forceinline__ void gl2lds16(const void* g, void* l) {
    __builtin_amdgcn_global_load_lds(
        (const __attribute__((address_space(1))) unsigned int*)g,
        (__attribute__((address_space(3))) unsigned int*)l, 16, 0, 0);
}

// ---------------- MFMA f16 GEMM, double-buffered + counted vmcnt ----------------
// (round-10 proven version)
__global__ __launch_bounds__(256) void gemm_mfma(
    const _Float16* __restrict__ A,
    const _Float16* __restrict__ Bt,
    const float* __restrict__ bias,
    _Float16* __restrict__ C0, _Float16* __restrict__ C1,
    int M, int N, int K, int ntn)
{
    __shared__ __align__(16) char smem[128 * 144 * 2];   // 36864 B
    _Float16* As = (_Float16*)smem;                      // [2][4096]
    _Float16* Bs = (_Float16*)(smem + 16384);            // [2][4096]
    const int tid  = threadIdx.x;
    const int lane = tid & 63;
    const int wave = tid >> 6;

    // bijective XCD-chunked swizzle (m204)
    const int nwg = gridDim.x;
    const int q = nwg >> 3, r = nwg & 7;
    const int xcd = blockIdx.x & 7, jj = blockIdx.x >> 3;
    const int swid = (xcd < r ? xcd * (q + 1) : r * (q + 1) + (xcd - r) * q) + jj;
    const int brow = (swid / ntn) * 128;
    const int bcol = (swid % ntn) * 128;

    f32x4 acc[4][4] = {};
    const int wr = (wave >> 1) * 64;
    const int wc = (wave & 1) * 64;
    const int swz = (lane >> 4) ^ ((lane >> 1) & 3);   // read-side swizzled k-chunk

    const int s0 = wave * 64 + lane;
    const int s1 = 256 + wave * 64 + lane;
    const int row0 = s0 >> 2, kc0 = (s0 & 3) ^ ((s0 >> 3) & 3);
    const int row1 = s1 >> 2, kc1 = (s1 & 3) ^ ((s1 >> 3) & 3);
    const _Float16* a0 = A + (size_t)(brow + row0) * K + kc0 * 8;
    const _Float16* a1 = A + (size_t)(brow + row1) * K + kc1 * 8;
    const _Float16* b0 = Bt + (size_t)(bcol + row0) * K + kc0 * 8;
    const _Float16* b1 = Bt + (size_t)(bcol + row1) * K + kc1 * 8;

#define STAGE(buf, k0) do {                                          \
        gl2lds16(a0 + (k0), &As[(buf) * 4096 + wave * 512]);         \
        gl2lds16(b0 + (k0), &Bs[(buf) * 4096 + wave * 512]);         \
        gl2lds16(a1 + (k0), &As[(buf) * 4096 + 2048 + wave * 512]);  \
        gl2lds16(b1 + (k0), &Bs[(buf) * 4096 + 2048 + wave * 512]);  \
    } while (0)

    STAGE(0, 0);
    const int nt = K >> 5;
    int cur = 0;
    for (int t = 0; t < nt; ++t) {
        if (t + 1 < nt) {
            STAGE(cur ^ 1, (t + 1) * 32);
            asm volatile("s_waitcnt vmcnt(4)" ::: "memory");
        } else {
            asm volatile("s_waitcnt vmcnt(0)" ::: "memory");
        }
        __builtin_amdgcn_s_barrier();
        __builtin_amdgcn_sched_barrier(0);
        h8 af[4], bfr[4];
        #pragma unroll
        for (int m = 0; m < 4; ++m)
            af[m] = *(const h8*)&As[cur * 4096 + (wr + m * 16 + (lane & 15)) * 32 + swz * 8];
        #pragma unroll
        for (int n = 0; n < 4; ++n)
            bfr[n] = *(const h8*)&Bs[cur * 4096 + (wc + n * 16 + (lane & 15)) * 32 + swz * 8];
        #pragma unroll
        for (int m = 0; m < 4; ++m)
            #pragma unroll
            for (int n = 0; n < 4; ++n)
                acc[m][n] = __builtin_amdgcn_mfma_f32_16x16x32_f16(
                    af[m], bfr[n], acc[m][n], 0, 0, 0);
        __builtin_amdgcn_s_barrier();
        cur ^= 1;
    }
#undef STAGE

    // ---- epilogue: acc -> LDS (pitch 144) -> coalesced 16B stores ----
    __syncthreads();
    _Float16* Cs = (_Float16*)smem;      // 128 x 144 f16 tile
    #pragma unroll
    for (int m = 0; m < 4; ++m) {
        int rl0 = wr + m * 16 + (lane >> 4) * 4;
        #pragma unroll
        for (int n = 0; n < 4; ++n) {
            int cl = wc + n * 16 + (lane & 15);
            float bv = bias ? bias[bcol + cl] : 0.f;
            #pragma unroll
            for (int j = 0; j < 4; ++j)
                Cs[(rl0 + j) * 144 + cl] = (_Float16)(acc[m][n][j] + bv);
        }
    }
    __syncthreads();

    const int half = N >> 1;
    const int c8 = (tid & 15) * 8;
    #pragma unroll
    for (int p = 0; p < 8; ++p) {
        int rl = p * 16 + (tid >> 4);
        int rr = brow + rl;
        if (rr >= M) continue;
        h8 vv = *(const h8*)&Cs[rl * 144 + c8];
        int c = bcol + c8;
        if (C1) {
            if (c < half) *(h8*)&C0[(size_t)rr * half + c] = vv;
            else          *(h8*)&C1[(size_t)rr * half + (c - half)] = vv;
        } else {
            *(h8*)&C0[(size_t)rr * N + c] = vv;
        }
    }
}

// ---------------- one-shot prep: converts, transposes, pads, bias packing ----
__global__ __launch_bounds__(256) void prep_all(
    const float* __restrict__ x,
    const float* __restrict__ Wl1, const float* __restrict__ Wr1,
    const float* __restrict__ Wl2, const float* __restrict__ Wr2,
    const float* __restrict__ We1, const float* __restrict__ We2,
    const float* __restrict__ relations,
    const float* __restrict__ bl1, const float* __restrict__ br1,
    const float* __restrict__ bl2, const float* __restrict__ br2,
    _Float16* __restrict__ xh, _Float16* __restrict__ hh,
    _Float16* __restrict__ Bt1, _Float16* __restrict__ Bt2,
    _Float16* __restrict__ BtE, _Float16* __restrict__ relh,
    float* __restrict__ pb1, float* __restrict__ pb2)
{
    constexpr long SXV   = (long)NN * INF_ / 4;
    constexpr long nXP   = (long)(MPAD - NN) * 128;
    constexpr long nHP   = (long)(MPAD - NN) * 256;
    constexpr long nW1   = 128 * 256;
    constexpr long nW2   = 256 * 512;
    constexpr long nWe1  = 128 * 256;
    constexpr long nWe2  = 128 * 512;
    constexpr long nRel  = (long)NR * 128;
    constexpr long nRelP = (512 - NR) * 128;
    constexpr long TOT = SXV + nXP + nHP + 2 * nW1 + 2 * nW2 + nWe1 + nWe2
                       + nRel + nRelP + 512 + 1024;

    for (long i = (long)blockIdx.x * 256 + threadIdx.x; i < TOT;
         i += (long)gridDim.x * 256) {
        long j = i;
        if (j < SXV) {
            float4 v = ((const float4*)x)[j];
            h4 o = {(_Float16)v.x, (_Float16)v.y, (_Float16)v.z, (_Float16)v.w};
            ((h4*)xh)[j] = o;
            continue;
        }
        j -= SXV;
        if (j < nXP) { xh[(long)NN * 128 + j] = (_Float16)0.f; continue; }
        j -= nXP;
        if (j < nHP) { hh[(long)NN * 256 + j] = (_Float16)0.f; continue; }
        j -= nHP;
        if (j < nW1) { long k = j >> 8, n = j & 255; Bt1[n * 128 + k] = (_Float16)Wl1[j]; continue; }
        j -= nW1;
        if (j < nW1) { long k = j >> 8, n = j & 255; Bt1[(256 + n) * 128 + k] = (_Float16)Wr1[j]; continue; }
        j -= nW1;
        if (j < nW2) { long k = j >> 9, n = j & 511; Bt2[n * 256 + k] = (_Float16)Wl2[j]; continue; }
        j -= nW2;
        if (j < nW2) { long k = j >> 9, n = j & 511; Bt2[(512 + n) * 256 + k] = (_Float16)Wr2[j]; continue; }
        j -= nW2;
        if (j < nWe1) { long k = j >> 8, n = j & 255; BtE[n * 128 + k] = (_Float16)We1[j]; continue; }
        j -= nWe1;
        if (j < nWe2) { long k = j >> 9, n = j & 511; BtE[(256 + n) * 128 + k] = (_Float16)We2[j]; continue; }
        j -= nWe2;
        if (j < nRel) { relh[j] = (_Float16)relations[j]; continue; }
        j -= nRel;
        if (j < nRelP) { relh[nRel + j] = (_Float16)0.f; continue; }
        j -= nRelP;
        if (j < 512) { pb1[j] = (j < 256) ? bl1[j] : br1[j - 256]; continue; }
        j -= 512;
        pb2[j] = (j < 512) ? bl2[j] : br2[j - 512];
    }
}

// ---------------- CSR build ----------------
__global__ void count_deg(const int* __restrict__ dst, int* __restrict__ deg, int E)
{
    int i = blockIdx.x * blockDim.x + threadIdx.x;
    if (i < E) atomicAdd(&deg[dst[i]], 1);
}

__global__ __launch_bounds__(256) void scan_block_sums(
    const int* __restrict__ deg, int* __restrict__ bsum, int n)
{
    __shared__ int s[256];
    int i = blockIdx.x * 256 + threadIdx.x;
    s[threadIdx.x] = (i < n) ? deg[i] : 0;
    __syncthreads();
    for (int o = 128; o > 0; o >>= 1) {
        if (threadIdx.x < o) s[threadIdx.x] += s[threadIdx.x + o];
        __syncthreads();
    }
    if (threadIdx.x == 0) bsum[blockIdx.x] = s[0];
}

__global__ __launch_bounds__(256) void scan_bsums(
    const int* __restrict__ bsum, int* __restrict__ boff, int nb)
{
    __shared__ int s[256];
    int v = (threadIdx.x < nb) ? bsum[threadIdx.x] : 0;
    s[threadIdx.x] = v;
    __syncthreads();
    for (int o = 1; o < 256; o <<= 1) {
        int t = (threadIdx.x >= o) ? s[threadIdx.x - o] : 0;
        __syncthreads();
        s[threadIdx.x] += t;
        __syncthreads();
    }
    if (threadIdx.x < nb) boff[threadIdx.x] = s[threadIdx.x] - v; // exclusive
}

__global__ __launch_bounds__(256) void scan_final(
    const int* __restrict__ deg, const int* __restrict__ boff,
    int* __restrict__ offsets, int n)
{
    __shared__ int s[256];
    int i = blockIdx.x * 256 + threadIdx.x;
    int v = (i < n) ? deg[i] : 0;
    s[threadIdx.x] = v;
    __syncthreads();
    for (int o = 1; o < 256; o <<= 1) {
        int t = (threadIdx.x >= o) ? s[threadIdx.x - o] : 0;
        __syncthreads();
        s[threadIdx.x] += t;
        __syncthreads();
    }
    int incl = s[threadIdx.x];
    int excl = incl - v;
    if (i < n) offsets[i] = boff[blockIdx.x] + excl;
    if (i == n - 1) offsets[n] = boff[blockIdx.x] + incl;
}

__global__ void fill_adj(const int* __restrict__ src, const int* __restrict__ rel,
                         const int* __restrict__ dst, const int* __restrict__ offsets,
                         int* __restrict__ cursor,
                         int2* __restrict__ adj, int E)
{
    int e = blockIdx.x * blockDim.x + threadIdx.x;
    if (e < E) {
        int d = dst[e];
        int p = atomicAdd(&cursor[d], 1);
        adj[offsets[d] + p] = make_int2(src[e], rel[e]);
    }
}

// ---------------- fused per-node GATv2 attention (1 wave/block, batch-8) -----
template <int CPH, bool CONCAT>
__global__ __launch_bounds__(64) void gat_node(
    const _Float16* __restrict__ xl,    // [n][HC] source-transform rows (gathered)
    const _Float16* __restrict__ xr,    // [n][HC] dest-transform rows
    const _Float16* __restrict__ erel,  // [NR rows][ldE] relations@We slice
    int ldE,
    const int2* __restrict__ adj,       // (src, rel) pairs, CSR by dst
    const int* __restrict__ offsets,
    const float* __restrict__ att,      // [HC] f32
    const float* __restrict__ bias,     // CONCAT ? [HC] : [CPH]
    void* __restrict__ out, int n)
{
    constexpr int HC  = NH * CPH;
    constexpr int VPL = HC / 64;
    constexpr int NP  = VPL / 2;
    const int lane = threadIdx.x;
    const int v = blockIdx.x;
    if (v >= n) return;
    const int loff = lane * VPL;

    h2 xlv[NP], xrv[NP], attp[NP], acc[NP];
    load_h<NP>(xl + (size_t)v * HC + loff, xlv);
    load_h<NP>(xr + (size_t)v * HC + loff, xrv);
    #pragma unroll
    for (int p = 0; p < NP; ++p) {
        attp[p][0] = (_Float16)att[loff + 2 * p];
        attp[p][1] = (_Float16)att[loff + 2 * p + 1];
        acc[p] = xlv[p];
    }

    // self loop logit
    float pS = 0.f;
    #pragma unroll
    for (int p = 0; p < NP; ++p) pS = fdot2a(lrelu2(xlv[p] + xrv[p]), attp[p], pS);
    pS += __shfl_xor(pS, 1);
    pS += __shfl_xor(pS, 2);
    pS += __shfl_xor(pS, 4);
    pS += __shfl_xor(pS, 8);
    float m_run = pS, l_run = 1.f;

    const int beg = offsets[v], end = offsets[v + 1];
    int idx = beg;

    // ---- batch-8: 16 row-gathers in flight per wave ----
    for (; idx + 8 <= end; idx += 8) {
        int2 ed[8];
        #pragma unroll
        for (int k = 0; k < 8; ++k) ed[k] = adj[idx + k];
        h2 xs[8][NP], ee[8][NP];
        #pragma unroll
        for (int k = 0; k < 8; ++k) {
            load_h<NP>(xl + (size_t)ed[k].x * HC + loff, xs[k]);
            load_h<NP>(erel + (size_t)ed[k].y * ldE + loff, ee[k]);
        }
        float pp[8] = {};
        #pragma unroll
        for (int p = 0; p < NP; ++p)
            #pragma unroll
            for (int k = 0; k < 8; ++k)
                pp[k] = fdot2a(lrelu2(xs[k][p] + xrv[p] + ee[k][p]), attp[p], pp[k]);
        #pragma unroll
        for (int msk = 1; msk <= 8; msk <<= 1)
            #pragma unroll
            for (int k = 0; k < 8; ++k) pp[k] += __shfl_xor(pp[k], msk);
        float mx = m_run;
        #pragma unroll
        for (int k = 0; k < 8; ++k) mx = fmaxf(mx, pp[k]);
        float sc = __expf(m_run - mx);
        float w[8], lsum = 0.f;
        #pragma unroll
        for (int k = 0; k < 8; ++k) { w[k] = __expf(pp[k] - mx); lsum += w[k]; }
        l_run = l_run * sc + lsum;
        h2 sc2 = b2(sc);
        #pragma unroll
        for (int p = 0; p < NP; ++p) {
            h2 a = acc[p] * sc2;
            #pragma unroll
            for (int k = 0; k < 8; ++k) a += xs[k][p] * b2(w[k]);
            acc[p] = a;
        }
        m_run = mx;
    }

    // ---- batch-4 ----
    for (; idx + 4 <= end; idx += 4) {
        int2 ed[4];
        #pragma unroll
        for (int k = 0; k < 4; ++k) ed[k] = adj[idx + k];
        h2 xs[4][NP], ee[4][NP];
        #pragma unroll
        for (int k = 0; k < 4; ++k) {
            load_h<NP>(xl + (size_t)ed[k].x * HC + loff, xs[k]);
            load_h<NP>(erel + (size_t)ed[k].y * ldE + loff, ee[k]);
        }
        float pp[4] = {};
        #pragma unroll
        for (int p = 0; p < NP; ++p)
            #pragma unroll
            for (int k = 0; k < 4; ++k)
                pp[k] = fdot2a(lrelu2(xs[k][p] + xrv[p] + ee[k][p]), attp[p], pp[k]);
        #pragma unroll
        for (int msk = 1; msk <= 8; msk <<= 1)
            #pragma unroll
            for (int k = 0; k < 4; ++k) pp[k] += __shfl_xor(pp[k], msk);
        float mx = m_run;
        #pragma unroll
        for (int k = 0; k < 4; ++k) mx = fmaxf(mx, pp[k]);
        float sc = __expf(m_run - mx);
        float w[4], lsum = 0.f;
        #pragma unroll
        for (int k = 0; k < 4; ++k) { w[k] = __expf(pp[k] - mx); lsum += w[k]; }
        l_run = l_run * sc + lsum;
        h2 sc2 = b2(sc);
        #pragma unroll
        for (int p = 0; p < NP; ++p) {
            h2 a = acc[p] * sc2;
            #pragma unroll
            for (int k = 0; k < 4; ++k) a += xs[k][p] * b2(w[k]);
            acc[p] = a;
        }
        m_run = mx;
    }

    // ---- scalar tail ----
    for (; idx < end; ++idx) {
        int2 ed = adj[idx];
        h2 xs0[NP], e0[NP];
        load_h<NP>(xl + (size_t)ed.x * HC + loff, xs0);
        load_h<NP>(erel + (size_t)ed.y * ldE + loff, e0);
        float p0 = 0.f;
        #pragma unroll
        for (int p = 0; p < NP; ++p)
            p0 = fdot2a(lrelu2(xs0[p] + xrv[p] + e0[p]), attp[p], p0);
        p0 += __shfl_xor(p0, 1);
        p0 += __shfl_xor(p0, 2);
        p0 += __shfl_xor(p0, 4);
        p0 += __shfl_xor(p0, 8);
        float mx = fmaxf(m_run, p0);
        float sc = __expf(m_run - mx);
        float w0 = __expf(p0 - mx);
        l_run = l_run * sc + w0;
        h2 sc2 = b2(sc), w02 = b2(w0);
        #pragma unroll
        for (int p = 0; p < NP; ++p) acc[p] = acc[p] * sc2 + xs0[p] * w02;
        m_run = mx;
    }

    float inv = 1.f / l_run;
    if constexpr (CONCAT) {
        _Float16* ob = (_Float16*)out + (size_t)v * HC + loff;
        if constexpr (NP == 2) {
            h4 o;
            #pragma unroll
            for (int p = 0; p < NP; ++p) {
                o[2 * p]     = (_Float16)((float)acc[p][0] * inv + bias[loff + 2 * p]);
                o[2 * p + 1] = (_Float16)((float)acc[p][1] * inv + bias[loff + 2 * p + 1]);
            }
            *(h4*)ob = o;
        } else {
            h8 o;
            #pragma unroll
            for (int p = 0; p < NP; ++p) {
                o[2 * p]     = (_Float16)((float)acc[p][0] * inv + bias[loff + 2 * p]);
                o[2 * p + 1] = (_Float16)((float)acc[p][1] * inv + bias[loff + 2 * p + 1]);
            }
            *(h8*)ob = o;
        }
    } else {
        float* of = (float*)out;
        float t[VPL];
        #pragma unroll
        for (int j = 0; j < VPL; ++j) {
            t[j] = (float)acc[j / 2][j & 1] * inv;
            t[j] += __shfl_xor(t[j], 16);
            t[j] += __shfl_xor(t[j], 32);
        }
        if (lane < 16) {
            #pragma unroll
            for (int j = 0; j < VPL; ++j)
                of[(size_t)v * CPH + lane * VPL + j] = 0.25f * t[j] + bias[lane * VPL + j];
        }
    }
}

// ---------------- host launcher ----------------
extern "C" void kernel_launch(void* const* d_in, const int* in_sizes, int n_in,
                              void* d_out, int out_size, void* d_ws, size_t ws_size,
                              hipStream_t stream)
{
    const float* x         = (const float*)d_in[0];
    const int*   ei        = (const int*)d_in[1];
    const float* relations = (const float*)d_in[2];
    const float* Wl1  = (const float*)d_in[3];
    const float* bl1  = (const float*)d_in[4];
    const float* Wr1  = (const float*)d_in[5];
    const float* br1  = (const float*)d_in[6];
    const float* We1  = (const float*)d_in[7];
    const float* att1 = (const float*)d_in[8];
    const float* bias1= (const float*)d_in[9];
    const float* Wl2  = (const float*)d_in[10];
    const float* bl2  = (const float*)d_in[11];
    const float* Wr2  = (const float*)d_in[12];
    const float* br2  = (const float*)d_in[13];
    const float* We2  = (const float*)d_in[14];
    const float* att2 = (const float*)d_in[15];
    const float* bias2= (const float*)d_in[16];
    float* out = (float*)d_out;

    const int* src = ei;
    const int* rel = ei + NE;
    const int* dst = ei + 2 * NE;

    // ---- workspace layout (f16 = _Float16) ----
    _Float16* xh   = (_Float16*)d_ws;                  // MPAD*128
    _Float16* hh   = xh + (size_t)MPAD * 128;          // MPAD*256
    _Float16* xl1  = hh + (size_t)MPAD * 256;          // NN*256
    _Float16* xr1  = xl1 + (size_t)NN * 256;           // NN*256
    _Float16* xl2  = xr1 + (size_t)NN * 256;           // NN*512
    _Float16* xr2  = xl2 + (size_t)NN * 512;           // NN*512
    _Float16* Bt1  = xr2 + (size_t)NN * 512;           // 512*128
    _Float16* Bt2  = Bt1 + 512 * 128;                  // 1024*256
    _Float16* BtE  = Bt2 + 1024 * 256;                 // 768*128
    _Float16* relh = BtE + 768 * 128;                  // 512*128
    _Float16* erelC= relh + 512 * 128;                 // 512*768 (500 used)
    float* pb1     = (float*)(erelC + 512 * 768);      // 512
    float* pb2     = pb1 + 512;                        // 1024
    int* deg     = (int*)(pb2 + 1024);
    int* cursor  = deg + NN;
    int* offsets = cursor + NN;       // NN+1
    int* bsum    = offsets + NN + 1;  // 256
    int* boff    = bsum + 256;        // 256
    int2* adj    = (int2*)(boff + 256);  // NE pairs

    const int NB = (NN + 255) / 256;  // 196
    const int EB = (NE + 255) / 256;

    // --- zero deg+cursor (adjacent) ---
    hipMemsetAsync(deg, 0, (size_t)2 * NN * sizeof(int), stream);

    // --- one-shot prep (converts/transposes/pads/bias packing) ---
    prep_all<<<2048, 256, 0, stream>>>(x, Wl1, Wr1, Wl2, Wr2, We1, We2, relations,
                                       bl1, br1, bl2, br2,
                                       xh, hh, Bt1, Bt2, BtE, relh, pb1, pb2);

    // --- CSR by destination ---
    count_deg<<<EB, 256, 0, stream>>>(dst, deg, NE);
    scan_block_sums<<<NB, 256, 0, stream>>>(deg, bsum, NN);
    scan_bsums<<<1, 256, 0, stream>>>(bsum, boff, NB);
    scan_final<<<NB, 256, 0, stream>>>(deg, boff, offsets, NN);
    fill_adj<<<EB, 256, 0, stream>>>(src, rel, dst, offsets, cursor, adj, NE);

    // --- relation tables: erelC[500 x 768] = relations @ [We1 | We2] ---
    gemm_mfma<<<4 * 6, 256, 0, stream>>>(relh, BtE, nullptr, erelC, nullptr,
                                         NR, 768, 128, 6);

    // --- layer 1 transform: xl1 = x@Wl1+bl1, xr1 = x@Wr1+br1 (one GEMM) ---
    gemm_mfma<<<(MPAD / 128) * 4, 256, 0, stream>>>(xh, Bt1, pb1, xl1, xr1,
                                                    NN, 512, 128, 4);

    // --- layer 1 attention -> h (f16); 1 wave per block ---
    gat_node<HIDC, true><<<NN, 64, 0, stream>>>(
        xl1, xr1, erelC, 768, adj, offsets, att1, bias1, hh, NN);

    // --- layer 2 transform: xl2 = h@Wl2+bl2, xr2 = h@Wr2+br2 ---
    gemm_mfma<<<(MPAD / 128) * 8, 256, 0, stream>>>(hh, Bt2, pb2, xl2, xr2,
                                                    NN, 1024, 256, 8);

    // --- layer 2 attention (mean over heads) -> out ---
    gat_node<OUTC, false><<<NN, 64, 0, stream>>>(
        xl2, xr2, erelC + 256, 768, adj, offsets, att2, bias2, out, NN);
}

// Round 13
// 248.323 us; speedup vs baseline: 1.0862x; 1.0349x over previous
//
#include <hip/hip_runtime.h>
#include <math.h>

constexpr int NN   = 50000;   // nodes
constexpr int NE   = 400000;  // edges
constexpr int NR   = 500;     // relations
constexpr int INF_ = 128;     // input feat
constexpr int HIDC = 64;      // layer1 per-head channels
constexpr int NH   = 4;       // heads
constexpr int OUTC = 128;     // layer2 per-head channels
constexpr int MPAD = 50048;   // 391 * 128

typedef __attribute__((ext_vector_type(2))) _Float16 h2;
typedef __attribute__((ext_vector_type(4))) _Float16 h4;
typedef __attribute__((ext_vector_type(8))) _Float16 h8;
typedef __attribute__((ext_vector_type(4))) float f32x4;

__device__ __forceinline__ h2 b2(float f) {
    _Float16 h = (_Float16)f;
    return (h2){h, h};
}

__device__ __forceinline__ h2 lrelu2(h2 x) {
    h2 t = x * (h2){(_Float16)0.2f, (_Float16)0.2f};
#if __has_builtin(__builtin_elementwise_max)
    return __builtin_elementwise_max(x, t);
#else
    h2 r;
    r[0] = x[0] > t[0] ? x[0] : t[0];
    r[1] = x[1] > t[1] ? x[1] : t[1];
    return r;
#endif
}

__device__ __forceinline__ float fdot2a(h2 a, h2 b, float c) {
#if __has_builtin(__builtin_amdgcn_fdot2)
    return __builtin_amdgcn_fdot2(a, b, c, false);
#else
    return c + (float)a[0] * (float)b[0] + (float)a[1] * (float)b[1];
#endif
}

template <int NP>
__device__ __forceinline__ void load_h(const _Float16* p, h2* d) {
    if constexpr (NP == 2) {
        h4 t = *(const h4*)p;
        d[0] = (h2){t[0], t[1]}; d[1] = (h2){t[2], t[3]};
    } else {
        h8 t = *(const h8*)p;
        d[0] = (h2){t[0], t[1]}; d[1] = (h2){t[2], t[3]};
        d[2] = (h2){t[4], t[5]}; d[3] = (h2){t[6], t[7]};
    }
}

__device__ __forceinline__ void gl2lds16(const void* g, void* l) {
    __builtin_amdgcn_global_load_lds(
        (const __attribute__((address_space(1))) unsigned int*)g,
        (__attribute__((address_space(3))) unsigned int*)l, 16, 0, 0);
}

// ---------------- MFMA f16 GEMM, double-buffered + counted vmcnt ----------------
// (round-10 proven version: 128x128 tile, BK=32, XOR swizzle, 2-phase pipeline,
//  XCD-chunked block swizzle, LDS-staged coalesced epilogue)
__global__ __launch_bounds__(256) void gemm_mfma(
    const _Float16* __restrict__ A,
    const _Float16* __restrict__ Bt,
    const float* __restrict__ bias,
    _Float16* __restrict__ C0, _Float16* __restrict__ C1,
    int M, int N, int K, int ntn)
{
    __shared__ __align__(16) char smem[128 * 144 * 2];   // 36864 B
    _Float16* As = (_Float16*)smem;                      // [2][4096]
    _Float16* Bs = (_Float16*)(smem + 16384);            // [2][4096]
    const int tid  = threadIdx.x;
    const int lane = tid & 63;
    const int wave = tid >> 6;

    // bijective XCD-chunked swizzle (m204)
    const int nwg = gridDim.x;
    const int q = nwg >> 3, r = nwg & 7;
    const int xcd = blockIdx.x & 7, jj = blockIdx.x >> 3;
    const int swid = (xcd < r ? xcd * (q + 1) : r * (q + 1) + (xcd - r) * q) + jj;
    const int brow = (swid / ntn) * 128;
    const int bcol = (swid % ntn) * 128;

    f32x4 acc[4][4] = {};
    const int wr = (wave >> 1) * 64;
    const int wc = (wave & 1) * 64;
    const int swz = (lane >> 4) ^ ((lane >> 1) & 3);   // read-side swizzled k-chunk

    const int s0 = wave * 64 + lane;
    const int s1 = 256 + wave * 64 + lane;
    const int row0 = s0 >> 2, kc0 = (s0 & 3) ^ ((s0 >> 3) & 3);
    const int row1 = s1 >> 2, kc1 = (s1 & 3) ^ ((s1 >> 3) & 3);
    const _Float16* a0 = A + (size_t)(brow + row0) * K + kc0 * 8;
    const _Float16* a1 = A + (size_t)(brow + row1) * K + kc1 * 8;
    const _Float16* b0 = Bt + (size_t)(bcol + row0) * K + kc0 * 8;
    const _Float16* b1 = Bt + (size_t)(bcol + row1) * K + kc1 * 8;

#define STAGE(buf, k0) do {                                          \
        gl2lds16(a0 + (k0), &As[(buf) * 4096 + wave * 512]);         \
        gl2lds16(b0 + (k0), &Bs[(buf) * 4096 + wave * 512]);         \
        gl2lds16(a1 + (k0), &As[(buf) * 4096 + 2048 + wave * 512]);  \
        gl2lds16(b1 + (k0), &Bs[(buf) * 4096 + 2048 + wave * 512]);  \
    } while (0)

    STAGE(0, 0);
    const int nt = K >> 5;
    int cur = 0;
    for (int t = 0; t < nt; ++t) {
        if (t + 1 < nt) {
            STAGE(cur ^ 1, (t + 1) * 32);
            asm volatile("s_waitcnt vmcnt(4)" ::: "memory");
        } else {
            asm volatile("s_waitcnt vmcnt(0)" ::: "memory");
        }
        __builtin_amdgcn_s_barrier();
        __builtin_amdgcn_sched_barrier(0);
        h8 af[4], bfr[4];
        #pragma unroll
        for (int m = 0; m < 4; ++m)
            af[m] = *(const h8*)&As[cur * 4096 + (wr + m * 16 + (lane & 15)) * 32 + swz * 8];
        #pragma unroll
        for (int n = 0; n < 4; ++n)
            bfr[n] = *(const h8*)&Bs[cur * 4096 + (wc + n * 16 + (lane & 15)) * 32 + swz * 8];
        #pragma unroll
        for (int m = 0; m < 4; ++m)
            #pragma unroll
            for (int n = 0; n < 4; ++n)
                acc[m][n] = __builtin_amdgcn_mfma_f32_16x16x32_f16(
                    af[m], bfr[n], acc[m][n], 0, 0, 0);
        __builtin_amdgcn_s_barrier();
        cur ^= 1;
    }
#undef STAGE

    // ---- epilogue: acc -> LDS (pitch 144) -> coalesced 16B stores ----
    __syncthreads();
    _Float16* Cs = (_Float16*)smem;      // 128 x 144 f16 tile
    #pragma unroll
    for (int m = 0; m < 4; ++m) {
        int rl0 = wr + m * 16 + (lane >> 4) * 4;
        #pragma unroll
        for (int n = 0; n < 4; ++n) {
            int cl = wc + n * 16 + (lane & 15);
            float bv = bias ? bias[bcol + cl] : 0.f;
            #pragma unroll
            for (int j = 0; j < 4; ++j)
                Cs[(rl0 + j) * 144 + cl] = (_Float16)(acc[m][n][j] + bv);
        }
    }
    __syncthreads();

    const int half = N >> 1;
    const int c8 = (tid & 15) * 8;
    #pragma unroll
    for (int p = 0; p < 8; ++p) {
        int rl = p * 16 + (tid >> 4);
        int rr = brow + rl;
        if (rr >= M) continue;
        h8 vv = *(const h8*)&Cs[rl * 144 + c8];
        int c = bcol + c8;
        if (C1) {
            if (c < half) *(h8*)&C0[(size_t)rr * half + c] = vv;
            else          *(h8*)&C1[(size_t)rr * half + (c - half)] = vv;
        } else {
            *(h8*)&C0[(size_t)rr * N + c] = vv;
        }
    }
}

// ---------------- one-shot prep: converts, transposes, bias packing, deg count
// Pad rows of xh/hh/relh are NOT zeroed: the GEMM A-tiles that read them only
// produce C rows >= M, which the rr<M guard discards (0xAA f16 is finite).
__global__ __launch_bounds__(256) void prep_all(
    const float* __restrict__ x,
    const float* __restrict__ Wl1, const float* __restrict__ Wr1,
    const float* __restrict__ Wl2, const float* __restrict__ Wr2,
    const float* __restrict__ We1, const float* __restrict__ We2,
    const float* __restrict__ relations,
    const float* __restrict__ bl1, const float* __restrict__ br1,
    const float* __restrict__ bl2, const float* __restrict__ br2,
    const int* __restrict__ dst, int* __restrict__ deg,
    _Float16* __restrict__ xh,
    _Float16* __restrict__ Bt1, _Float16* __restrict__ Bt2,
    _Float16* __restrict__ BtE, _Float16* __restrict__ relh,
    float* __restrict__ pb1, float* __restrict__ pb2)
{
    constexpr long SXV   = (long)NN * INF_ / 4;
    constexpr long nW1   = 128 * 256;
    constexpr long nW2   = 256 * 512;
    constexpr long nWe1  = 128 * 256;
    constexpr long nWe2  = 128 * 512;
    constexpr long nRel  = (long)NR * 128;
    constexpr long TOT = SXV + 2 * nW1 + 2 * nW2 + nWe1 + nWe2
                       + nRel + 512 + 1024 + NE;

    for (long i = (long)blockIdx.x * 256 + threadIdx.x; i < TOT;
         i += (long)gridDim.x * 256) {
        long j = i;
        if (j < SXV) {
            float4 v = ((const float4*)x)[j];
            h4 o = {(_Float16)v.x, (_Float16)v.y, (_Float16)v.z, (_Float16)v.w};
            ((h4*)xh)[j] = o;
            continue;
        }
        j -= SXV;
        if (j < nW1) { long k = j >> 8, n = j & 255; Bt1[n * 128 + k] = (_Float16)Wl1[j]; continue; }
        j -= nW1;
        if (j < nW1) { long k = j >> 8, n = j & 255; Bt1[(256 + n) * 128 + k] = (_Float16)Wr1[j]; continue; }
        j -= nW1;
        if (j < nW2) { long k = j >> 9, n = j & 511; Bt2[n * 256 + k] = (_Float16)Wl2[j]; continue; }
        j -= nW2;
        if (j < nW2) { long k = j >> 9, n = j & 511; Bt2[(512 + n) * 256 + k] = (_Float16)Wr2[j]; continue; }
        j -= nW2;
        if (j < nWe1) { long k = j >> 8, n = j & 255; BtE[n * 128 + k] = (_Float16)We1[j]; continue; }
        j -= nWe1;
        if (j < nWe2) { long k = j >> 9, n = j & 511; BtE[(256 + n) * 128 + k] = (_Float16)We2[j]; continue; }
        j -= nWe2;
        if (j < nRel) { relh[j] = (_Float16)relations[j]; continue; }
        j -= nRel;
        if (j < 512) { pb1[j] = (j < 256) ? bl1[j] : br1[j - 256]; continue; }
        j -= 512;
        if (j < 1024) { pb2[j] = (j < 512) ? bl2[j] : br2[j - 512]; continue; }
        j -= 1024;
        atomicAdd(&deg[dst[j]], 1);   // count_deg fused
    }
}

// ---------------- CSR build ----------------
__global__ __launch_bounds__(256) void scan_block_sums(
    const int* __restrict__ deg, int* __restrict__ bsum, int n)
{
    __shared__ int s[256];
    int i = blockIdx.x * 256 + threadIdx.x;
    s[threadIdx.x] = (i < n) ? deg[i] : 0;
    __syncthreads();
    for (int o = 128; o > 0; o >>= 1) {
        if (threadIdx.x < o) s[threadIdx.x] += s[threadIdx.x + o];
        __syncthreads();
    }
    if (threadIdx.x == 0) bsum[blockIdx.x] = s[0];
}

__global__ __launch_bounds__(256) void scan_bsums(
    const int* __restrict__ bsum, int* __restrict__ boff, int nb)
{
    __shared__ int s[256];
    int v = (threadIdx.x < nb) ? bsum[threadIdx.x] : 0;
    s[threadIdx.x] = v;
    __syncthreads();
    for (int o = 1; o < 256; o <<= 1) {
        int t = (threadIdx.x >= o) ? s[threadIdx.x - o] : 0;
        __syncthreads();
        s[threadIdx.x] += t;
        __syncthreads();
    }
    if (threadIdx.x < nb) boff[threadIdx.x] = s[threadIdx.x] - v; // exclusive
}

__global__ __launch_bounds__(256) void scan_final(
    const int* __restrict__ deg, const int* __restrict__ boff,
    int* __restrict__ offsets, int n)
{
    __shared__ int s[256];
    int i = blockIdx.x * 256 + threadIdx.x;
    int v = (i < n) ? deg[i] : 0;
    s[threadIdx.x] = v;
    __syncthreads();
    for (int o = 1; o < 256; o <<= 1) {
        int t = (threadIdx.x >= o) ? s[threadIdx.x - o] : 0;
        __syncthreads();
        s[threadIdx.x] += t;
        __syncthreads();
    }
    int incl = s[threadIdx.x];
    int excl = incl - v;
    if (i < n) offsets[i] = boff[blockIdx.x] + excl;
    if (i == n - 1) offsets[n] = boff[blockIdx.x] + incl;
}

__global__ void fill_adj(const int* __restrict__ src, const int* __restrict__ rel,
                         const int* __restrict__ dst, const int* __restrict__ offsets,
                         int* __restrict__ cursor,
                         int2* __restrict__ adj, int E)
{
    int e = blockIdx.x * blockDim.x + threadIdx.x;
    if (e < E) {
        int d = dst[e];
        int p = atomicAdd(&cursor[d], 1);
        adj[offsets[d] + p] = make_int2(src[e], rel[e]);
    }
}

// ---------------- fused per-node GATv2 attention (1 wave/block, batch-4) -----
template <int CPH, bool CONCAT>
__global__ __launch_bounds__(64) void gat_node(
    const _Float16* __restrict__ xl,    // [n][HC] source-transform rows (gathered)
    const _Float16* __restrict__ xr,    // [n][HC] dest-transform rows
    const _Float16* __restrict__ erel,  // [NR rows][ldE] relations@We slice
    int ldE,
    const int2* __restrict__ adj,       // (src, rel) pairs, CSR by dst
    const int* __restrict__ offsets,
    const float* __restrict__ att,      // [HC] f32
    const float* __restrict__ bias,     // CONCAT ? [HC] : [CPH]
    void* __restrict__ out, int n)
{
    constexpr int HC  = NH * CPH;
    constexpr int VPL = HC / 64;
    constexpr int NP  = VPL / 2;
    const int lane = threadIdx.x;
    const int v = blockIdx.x;
    if (v >= n) return;
    const int loff = lane * VPL;

    h2 xlv[NP], xrv[NP], attp[NP], acc[NP];
    load_h<NP>(xl + (size_t)v * HC + loff, xlv);
    load_h<NP>(xr + (size_t)v * HC + loff, xrv);
    #pragma unroll
    for (int p = 0; p < NP; ++p) {
        attp[p][0] = (_Float16)att[loff + 2 * p];
        attp[p][1] = (_Float16)att[loff + 2 * p + 1];
        acc[p] = xlv[p];
    }

    // self loop logit
    float pS = 0.f;
    #pragma unroll
    for (int p = 0; p < NP; ++p) pS = fdot2a(lrelu2(xlv[p] + xrv[p]), attp[p], pS);
    pS += __shfl_xor(pS, 1);
    pS += __shfl_xor(pS, 2);
    pS += __shfl_xor(pS, 4);
    pS += __shfl_xor(pS, 8);
    float m_run = pS, l_run = 1.f;

    const int beg = offsets[v], end = offsets[v + 1];
    int idx = beg;
    for (; idx + 4 <= end; idx += 4) {
        int2 ed[4];
        #pragma unroll
        for (int k = 0; k < 4; ++k) ed[k] = adj[idx + k];
        h2 xs[4][NP], ee[4][NP];
        #pragma unroll
        for (int k = 0; k < 4; ++k) {
            load_h<NP>(xl + (size_t)ed[k].x * HC + loff, xs[k]);
            load_h<NP>(erel + (size_t)ed[k].y * ldE + loff, ee[k]);
        }
        float pp[4] = {};
        #pragma unroll
        for (int p = 0; p < NP; ++p)
            #pragma unroll
            for (int k = 0; k < 4; ++k)
                pp[k] = fdot2a(lrelu2(xs[k][p] + xrv[p] + ee[k][p]), attp[p], pp[k]);
        #pragma unroll
        for (int msk = 1; msk <= 8; msk <<= 1)
            #pragma unroll
            for (int k = 0; k < 4; ++k) pp[k] += __shfl_xor(pp[k], msk);
        float mx = m_run;
        #pragma unroll
        for (int k = 0; k < 4; ++k) mx = fmaxf(mx, pp[k]);
        float sc = __expf(m_run - mx);
        float w[4], lsum = 0.f;
        #pragma unroll
        for (int k = 0; k < 4; ++k) { w[k] = __expf(pp[k] - mx); lsum += w[k]; }
        l_run = l_run * sc + lsum;
        h2 sc2 = b2(sc);
        #pragma unroll
        for (int p = 0; p < NP; ++p) {
            h2 a = acc[p] * sc2;
            #pragma unroll
            for (int k = 0; k < 4; ++k) a += xs[k][p] * b2(w[k]);
            acc[p] = a;
        }
        m_run = mx;
    }
    for (; idx < end; ++idx) {
        int2 ed = adj[idx];
        h2 xs0[NP], e0[NP];
        load_h<NP>(xl + (size_t)ed.x * HC + loff, xs0);
        load_h<NP>(erel + (size_t)ed.y * ldE + loff, e0);
        float p0 = 0.f;
        #pragma unroll
        for (int p = 0; p < NP; ++p)
            p0 = fdot2a(lrelu2(xs0[p] + xrv[p] + e0[p]), attp[p], p0);
        p0 += __shfl_xor(p0, 1);
        p0 += __shfl_xor(p0, 2);
        p0 += __shfl_xor(p0, 4);
        p0 += __shfl_xor(p0, 8);
        float mx = fmaxf(m_run, p0);
        float sc = __expf(m_run - mx);
        float w0 = __expf(p0 - mx);
        l_run = l_run * sc + w0;
        h2 sc2 = b2(sc), w02 = b2(w0);
        #pragma unroll
        for (int p = 0; p < NP; ++p) acc[p] = acc[p] * sc2 + xs0[p] * w02;
        m_run = mx;
    }

    float inv = 1.f / l_run;
    if constexpr (CONCAT) {
        _Float16* ob = (_Float16*)out + (size_t)v * HC + loff;
        if constexpr (NP == 2) {
            h4 o;
            #pragma unroll
            for (int p = 0; p < NP; ++p) {
                o[2 * p]     = (_Float16)((float)acc[p][0] * inv + bias[loff + 2 * p]);
                o[2 * p + 1] = (_Float16)((float)acc[p][1] * inv + bias[loff + 2 * p + 1]);
            }
            *(h4*)ob = o;
        } else {
            h8 o;
            #pragma unroll
            for (int p = 0; p < NP; ++p) {
                o[2 * p]     = (_Float16)((float)acc[p][0] * inv + bias[loff + 2 * p]);
                o[2 * p + 1] = (_Float16)((float)acc[p][1] * inv + bias[loff + 2 * p + 1]);
            }
            *(h8*)ob = o;
        }
    } else {
        float* of = (float*)out;
        float t[VPL];
        #pragma unroll
        for (int j = 0; j < VPL; ++j) {
            t[j] = (float)acc[j / 2][j & 1] * inv;
            t[j] += __shfl_xor(t[j], 16);
            t[j] += __shfl_xor(t[j], 32);
        }
        if (lane < 16) {
            #pragma unroll
            for (int j = 0; j < VPL; ++j)
                of[(size_t)v * CPH + lane * VPL + j] = 0.25f * t[j] + bias[lane * VPL + j];
        }
    }
}

// ---------------- host launcher ----------------
extern "C" void kernel_launch(void* const* d_in, const int* in_sizes, int n_in,
                              void* d_out, int out_size, void* d_ws, size_t ws_size,
                              hipStream_t stream)
{
    const float* x         = (const float*)d_in[0];
    const int*   ei        = (const int*)d_in[1];
    const float* relations = (const float*)d_in[2];
    const float* Wl1  = (const float*)d_in[3];
    const float* bl1  = (const float*)d_in[4];
    const float* Wr1  = (const float*)d_in[5];
    const float* br1  = (const float*)d_in[6];
    const float* We1  = (const float*)d_in[7];
    const float* att1 = (const float*)d_in[8];
    const float* bias1= (const float*)d_in[9];
    const float* Wl2  = (const float*)d_in[10];
    const float* bl2  = (const float*)d_in[11];
    const float* Wr2  = (const float*)d_in[12];
    const float* br2  = (const float*)d_in[13];
    const float* We2  = (const float*)d_in[14];
    const float* att2 = (const float*)d_in[15];
    const float* bias2= (const float*)d_in[16];
    float* out = (float*)d_out;

    const int* src = ei;
    const int* rel = ei + NE;
    const int* dst = ei + 2 * NE;

    // ---- workspace layout (f16 = _Float16) ----
    _Float16* xh   = (_Float16*)d_ws;                  // MPAD*128
    _Float16* hh   = xh + (size_t)MPAD * 128;          // MPAD*256
    _Float16* xl1  = hh + (size_t)MPAD * 256;          // NN*256
    _Float16* xr1  = xl1 + (size_t)NN * 256;           // NN*256
    _Float16* xl2  = xr1 + (size_t)NN * 256;           // NN*512
    _Float16* xr2  = xl2 + (size_t)NN * 512;           // NN*512
    _Float16* Bt1  = xr2 + (size_t)NN * 512;           // 512*128
    _Float16* Bt2  = Bt1 + 512 * 128;                  // 1024*256
    _Float16* BtE  = Bt2 + 1024 * 256;                 // 768*128
    _Float16* relh = BtE + 768 * 128;                  // 512*128 (500 used)
    _Float16* erelC= relh + 512 * 128;                 // 512*768 (500 used)
    float* pb1     = (float*)(erelC + 512 * 768);      // 512
    float* pb2     = pb1 + 512;                        // 1024
    int* deg     = (int*)(pb2 + 1024);
    int* cursor  = deg + NN;
    int* offsets = cursor + NN;       // NN+1
    int* bsum    = offsets + NN + 1;  // 256
    int* boff    = bsum + 256;        // 256
    int2* adj    = (int2*)(boff + 256);  // NE pairs

    const int NB = (NN + 255) / 256;  // 196
    const int EB = (NE + 255) / 256;

    // --- zero deg+cursor (adjacent) ---
    hipMemsetAsync(deg, 0, (size_t)2 * NN * sizeof(int), stream);

    // --- one-shot prep (converts/transposes/bias packing + degree count) ---
    prep_all<<<2048, 256, 0, stream>>>(x, Wl1, Wr1, Wl2, Wr2, We1, We2, relations,
                                       bl1, br1, bl2, br2, dst, deg,
                                       xh, Bt1, Bt2, BtE, relh, pb1, pb2);

    // --- CSR by destination ---
    scan_block_sums<<<NB, 256, 0, stream>>>(deg, bsum, NN);
    scan_bsums<<<1, 256, 0, stream>>>(bsum, boff, NB);
    scan_final<<<NB, 256, 0, stream>>>(deg, boff, offsets, NN);
    fill_adj<<<EB, 256, 0, stream>>>(src, rel, dst, offsets, cursor, adj, NE);

    // --- relation tables: erelC[500 x 768] = relations @ [We1 | We2] ---
    gemm_mfma<<<4 * 6, 256, 0, stream>>>(relh, BtE, nullptr, erelC, nullptr,
                                         NR, 768, 128, 6);

    // --- layer 1 transform: xl1 = x@Wl1+bl1, xr1 = x@Wr1+br1 (one GEMM) ---
    gemm_mfma<<<(MPAD / 128) * 4, 256, 0, stream>>>(xh, Bt1, pb1, xl1, xr1,
                                                    NN, 512, 128, 4);

    // --- layer 1 attention -> h (f16); 1 wave per block ---
    gat_node<HIDC, true><<<NN, 64, 0, stream>>>(
        xl1, xr1, erelC, 768, adj, offsets, att1, bias1, hh, NN);

    // --- layer 2 transform: xl2 = h@Wl2+bl2, xr2 = h@Wr2+br2 ---
    gemm_mfma<<<(MPAD / 128) * 8, 256, 0, stream>>>(hh, Bt2, pb2, xl2, xr2,
                                                    NN, 1024, 256, 8);

    // --- layer 2 attention (mean over heads) -> out ---
    gat_node<OUTC, false><<<NN, 64, 0, stream>>>(
        xl2, xr2, erelC + 256, 768, adj, offsets, att2, bias2, out, NN);
}

// Round 15
// 247.105 us; speedup vs baseline: 1.0916x; 1.0049x over previous
//
#include <hip/hip_runtime.h>
#include <math.h>

constexpr int NN   = 50000;   // nodes
constexpr int NE   = 400000;  // edges
constexpr int NR   = 500;     // relations
constexpr int INF_ = 128;     // input feat
constexpr int HIDC = 64;      // layer1 per-head channels
constexpr int NH   = 4;       // heads
constexpr int OUTC = 128;     // layer2 per-head channels
constexpr int MPAD = 50048;   // 391 * 128

typedef __attribute__((ext_vector_type(2))) _Float16 h2;
typedef __attribute__((ext_vector_type(4))) _Float16 h4;
typedef __attribute__((ext_vector_type(8))) _Float16 h8;
typedef __attribute__((ext_vector_type(4))) float f32x4;

__device__ __forceinline__ h2 b2(float f) {
    _Float16 h = (_Float16)f;
    return (h2){h, h};
}

__device__ __forceinline__ h2 lrelu2(h2 x) {
    h2 t = x * (h2){(_Float16)0.2f, (_Float16)0.2f};
#if __has_builtin(__builtin_elementwise_max)
    return __builtin_elementwise_max(x, t);
#else
    h2 r;
    r[0] = x[0] > t[0] ? x[0] : t[0];
    r[1] = x[1] > t[1] ? x[1] : t[1];
    return r;
#endif
}

__device__ __forceinline__ float fdot2a(h2 a, h2 b, float c) {
#if __has_builtin(__builtin_amdgcn_fdot2)
    return __builtin_amdgcn_fdot2(a, b, c, false);
#else
    return c + (float)a[0] * (float)b[0] + (float)a[1] * (float)b[1];
#endif
}

template <int NP>
__device__ __forceinline__ void load_h(const _Float16* p, h2* d) {
    if constexpr (NP == 2) {
        h4 t = *(const h4*)p;
        d[0] = (h2){t[0], t[1]}; d[1] = (h2){t[2], t[3]};
    } else {
        h8 t = *(const h8*)p;
        d[0] = (h2){t[0], t[1]}; d[1] = (h2){t[2], t[3]};
        d[2] = (h2){t[4], t[5]}; d[3] = (h2){t[6], t[7]};
    }
}

// non-temporal variant: single-use stream reads bypass cache retention
template <int NP>
__device__ __forceinline__ void load_h_nt(const _Float16* p, h2* d) {
    if constexpr (NP == 2) {
        h4 t = __builtin_nontemporal_load((const h4*)p);
        d[0] = (h2){t[0], t[1]}; d[1] = (h2){t[2], t[3]};
    } else {
        h8 t = __builtin_nontemporal_load((const h8*)p);
        d[0] = (h2){t[0], t[1]}; d[1] = (h2){t[2], t[3]};
        d[2] = (h2){t[4], t[5]}; d[3] = (h2){t[6], t[7]};
    }
}

// adj pair as 8-byte integer (nontemporal builtin rejects HIP_vector_type)
__device__ __forceinline__ void adj_nt(const long long* p, int& s, int& r) {
    long long v = __builtin_nontemporal_load(p);
    s = (int)(v & 0xffffffffLL);
    r = (int)(v >> 32);
}

__device__ __forceinline__ void gl2lds16(const void* g, void* l) {
    __builtin_amdgcn_global_load_lds(
        (const __attribute__((address_space(1))) unsigned int*)g,
        (__attribute__((address_space(3))) unsigned int*)l, 16, 0, 0);
}

// ---------------- MFMA f16 GEMM, double-buffered + counted vmcnt ----------------
// (round-10 proven version: 128x128 tile, BK=32, XOR swizzle, 2-phase pipeline,
//  XCD-chunked block swizzle, LDS-staged coalesced epilogue)
__global__ __launch_bounds__(256) void gemm_mfma(
    const _Float16* __restrict__ A,
    const _Float16* __restrict__ Bt,
    const float* __restrict__ bias,
    _Float16* __restrict__ C0, _Float16* __restrict__ C1,
    int M, int N, int K, int ntn)
{
    __shared__ __align__(16) char smem[128 * 144 * 2];   // 36864 B
    _Float16* As = (_Float16*)smem;                      // [2][4096]
    _Float16* Bs = (_Float16*)(smem + 16384);            // [2][4096]
    const int tid  = threadIdx.x;
    const int lane = tid & 63;
    const int wave = tid >> 6;

    // bijective XCD-chunked swizzle (m204)
    const int nwg = gridDim.x;
    const int q = nwg >> 3, r = nwg & 7;
    const int xcd = blockIdx.x & 7, jj = blockIdx.x >> 3;
    const int swid = (xcd < r ? xcd * (q + 1) : r * (q + 1) + (xcd - r) * q) + jj;
    const int brow = (swid / ntn) * 128;
    const int bcol = (swid % ntn) * 128;

    f32x4 acc[4][4] = {};
    const int wr = (wave >> 1) * 64;
    const int wc = (wave & 1) * 64;
    const int swz = (lane >> 4) ^ ((lane >> 1) & 3);   // read-side swizzled k-chunk

    const int s0 = wave * 64 + lane;
    const int s1 = 256 + wave * 64 + lane;
    const int row0 = s0 >> 2, kc0 = (s0 & 3) ^ ((s0 >> 3) & 3);
    const int row1 = s1 >> 2, kc1 = (s1 & 3) ^ ((s1 >> 3) & 3);
    const _Float16* a0 = A + (size_t)(brow + row0) * K + kc0 * 8;
    const _Float16* a1 = A + (size_t)(brow + row1) * K + kc1 * 8;
    const _Float16* b0 = Bt + (size_t)(bcol + row0) * K + kc0 * 8;
    const _Float16* b1 = Bt + (size_t)(bcol + row1) * K + kc1 * 8;

#define STAGE(buf, k0) do {                                          \
        gl2lds16(a0 + (k0), &As[(buf) * 4096 + wave * 512]);         \
        gl2lds16(b0 + (k0), &Bs[(buf) * 4096 + wave * 512]);         \
        gl2lds16(a1 + (k0), &As[(buf) * 4096 + 2048 + wave * 512]);  \
        gl2lds16(b1 + (k0), &Bs[(buf) * 4096 + 2048 + wave * 512]);  \
    } while (0)

    STAGE(0, 0);
    const int nt = K >> 5;
    int cur = 0;
    for (int t = 0; t < nt; ++t) {
        if (t + 1 < nt) {
            STAGE(cur ^ 1, (t + 1) * 32);
            asm volatile("s_waitcnt vmcnt(4)" ::: "memory");
        } else {
            asm volatile("s_waitcnt vmcnt(0)" ::: "memory");
        }
        __builtin_amdgcn_s_barrier();
        __builtin_amdgcn_sched_barrier(0);
        h8 af[4], bfr[4];
        #pragma unroll
        for (int m = 0; m < 4; ++m)
            af[m] = *(const h8*)&As[cur * 4096 + (wr + m * 16 + (lane & 15)) * 32 + swz * 8];
        #pragma unroll
        for (int n = 0; n < 4; ++n)
            bfr[n] = *(const h8*)&Bs[cur * 4096 + (wc + n * 16 + (lane & 15)) * 32 + swz * 8];
        #pragma unroll
        for (int m = 0; m < 4; ++m)
            #pragma unroll
            for (int n = 0; n < 4; ++n)
                acc[m][n] = __builtin_amdgcn_mfma_f32_16x16x32_f16(
                    af[m], bfr[n], acc[m][n], 0, 0, 0);
        __builtin_amdgcn_s_barrier();
        cur ^= 1;
    }
#undef STAGE

    // ---- epilogue: acc -> LDS (pitch 144) -> coalesced 16B stores ----
    __syncthreads();
    _Float16* Cs = (_Float16*)smem;      // 128 x 144 f16 tile
    #pragma unroll
    for (int m = 0; m < 4; ++m) {
        int rl0 = wr + m * 16 + (lane >> 4) * 4;
        #pragma unroll
        for (int n = 0; n < 4; ++n) {
            int cl = wc + n * 16 + (lane & 15);
            float bv = bias ? bias[bcol + cl] : 0.f;
            #pragma unroll
            for (int j = 0; j < 4; ++j)
                Cs[(rl0 + j) * 144 + cl] = (_Float16)(acc[m][n][j] + bv);
        }
    }
    __syncthreads();

    const int half = N >> 1;
    const int c8 = (tid & 15) * 8;
    #pragma unroll
    for (int p = 0; p < 8; ++p) {
        int rl = p * 16 + (tid >> 4);
        int rr = brow + rl;
        if (rr >= M) continue;
        h8 vv = *(const h8*)&Cs[rl * 144 + c8];
        int c = bcol + c8;
        if (C1) {
            if (c < half) *(h8*)&C0[(size_t)rr * half + c] = vv;
            else          *(h8*)&C1[(size_t)rr * half + (c - half)] = vv;
        } else {
            *(h8*)&C0[(size_t)rr * N + c] = vv;
        }
    }
}

// ---------------- one-shot prep: converts, transposes, bias packing, deg count
__global__ __launch_bounds__(256) void prep_all(
    const float* __restrict__ x,
    const float* __restrict__ Wl1, const float* __restrict__ Wr1,
    const float* __restrict__ Wl2, const float* __restrict__ Wr2,
    const float* __restrict__ We1, const float* __restrict__ We2,
    const float* __restrict__ relations,
    const float* __restrict__ bl1, const float* __restrict__ br1,
    const float* __restrict__ bl2, const float* __restrict__ br2,
    const int* __restrict__ dst, int* __restrict__ deg,
    _Float16* __restrict__ xh,
    _Float16* __restrict__ Bt1, _Float16* __restrict__ Bt2,
    _Float16* __restrict__ BtE, _Float16* __restrict__ relh,
    float* __restrict__ pb1, float* __restrict__ pb2)
{
    constexpr long SXV   = (long)NN * INF_ / 4;
    constexpr long nW1   = 128 * 256;
    constexpr long nW2   = 256 * 512;
    constexpr long nWe1  = 128 * 256;
    constexpr long nWe2  = 128 * 512;
    constexpr long nRel  = (long)NR * 128;
    constexpr long TOT = SXV + 2 * nW1 + 2 * nW2 + nWe1 + nWe2
                       + nRel + 512 + 1024 + NE;

    for (long i = (long)blockIdx.x * 256 + threadIdx.x; i < TOT;
         i += (long)gridDim.x * 256) {
        long j = i;
        if (j < SXV) {
            float4 v = ((const float4*)x)[j];
            h4 o = {(_Float16)v.x, (_Float16)v.y, (_Float16)v.z, (_Float16)v.w};
            ((h4*)xh)[j] = o;
            continue;
        }
        j -= SXV;
        if (j < nW1) { long k = j >> 8, n = j & 255; Bt1[n * 128 + k] = (_Float16)Wl1[j]; continue; }
        j -= nW1;
        if (j < nW1) { long k = j >> 8, n = j & 255; Bt1[(256 + n) * 128 + k] = (_Float16)Wr1[j]; continue; }
        j -= nW1;
        if (j < nW2) { long k = j >> 9, n = j & 511; Bt2[n * 256 + k] = (_Float16)Wl2[j]; continue; }
        j -= nW2;
        if (j < nW2) { long k = j >> 9, n = j & 511; Bt2[(512 + n) * 256 + k] = (_Float16)Wr2[j]; continue; }
        j -= nW2;
        if (j < nWe1) { long k = j >> 8, n = j & 255; BtE[n * 128 + k] = (_Float16)We1[j]; continue; }
        j -= nWe1;
        if (j < nWe2) { long k = j >> 9, n = j & 511; BtE[(256 + n) * 128 + k] = (_Float16)We2[j]; continue; }
        j -= nWe2;
        if (j < nRel) { relh[j] = (_Float16)relations[j]; continue; }
        j -= nRel;
        if (j < 512) { pb1[j] = (j < 256) ? bl1[j] : br1[j - 256]; continue; }
        j -= 512;
        if (j < 1024) { pb2[j] = (j < 512) ? bl2[j] : br2[j - 512]; continue; }
        j -= 1024;
        atomicAdd(&deg[dst[j]], 1);   // count_deg fused
    }
}

// ---------------- CSR build ----------------
__global__ __launch_bounds__(256) void scan_block_sums(
    const int* __restrict__ deg, int* __restrict__ bsum, int n)
{
    __shared__ int s[256];
    int i = blockIdx.x * 256 + threadIdx.x;
    s[threadIdx.x] = (i < n) ? deg[i] : 0;
    __syncthreads();
    for (int o = 128; o > 0; o >>= 1) {
        if (threadIdx.x < o) s[threadIdx.x] += s[threadIdx.x + o];
        __syncthreads();
    }
    if (threadIdx.x == 0) bsum[blockIdx.x] = s[0];
}

__global__ __launch_bounds__(256) void scan_bsums(
    const int* __restrict__ bsum, int* __restrict__ boff, int nb)
{
    __shared__ int s[256];
    int v = (threadIdx.x < nb) ? bsum[threadIdx.x] : 0;
    s[threadIdx.x] = v;
    __syncthreads();
    for (int o = 1; o < 256; o <<= 1) {
        int t = (threadIdx.x >= o) ? s[threadIdx.x - o] : 0;
        __syncthreads();
        s[threadIdx.x] += t;
        __syncthreads();
    }
    if (threadIdx.x < nb) boff[threadIdx.x] = s[threadIdx.x] - v; // exclusive
}

__global__ __launch_bounds__(256) void scan_final(
    const int* __restrict__ deg, const int* __restrict__ boff,
    int* __restrict__ offsets, int n)
{
    __shared__ int s[256];
    int i = blockIdx.x * 256 + threadIdx.x;
    int v = (i < n) ? deg[i] : 0;
    s[threadIdx.x] = v;
    __syncthreads();
    for (int o = 1; o < 256; o <<= 1) {
        int t = (threadIdx.x >= o) ? s[threadIdx.x - o] : 0;
        __syncthreads();
        s[threadIdx.x] += t;
        __syncthreads();
    }
    int incl = s[threadIdx.x];
    int excl = incl - v;
    if (i < n) offsets[i] = boff[blockIdx.x] + excl;
    if (i == n - 1) offsets[n] = boff[blockIdx.x] + incl;
}

__global__ void fill_adj(const int* __restrict__ src, const int* __restrict__ rel,
                         const int* __restrict__ dst, const int* __restrict__ offsets,
                         int* __restrict__ cursor,
                         long long* __restrict__ adj, int E)
{
    int e = blockIdx.x * blockDim.x + threadIdx.x;
    if (e < E) {
        int d = dst[e];
        int p = atomicAdd(&cursor[d], 1);
        adj[offsets[d] + p] = ((long long)(unsigned)src[e])
                            | ((long long)rel[e] << 32);
    }
}

// ---------------- fused per-node GATv2 attention (1 wave/block, batch-4) -----
// NT hints: xr row (streamed once) + adj reads + final f32 out store bypass
// cache retention, protecting xl's L3 residency for the random gathers.
template <int CPH, bool CONCAT>
__global__ __launch_bounds__(64) void gat_node(
    const _Float16* __restrict__ xl,    // [n][HC] source-transform rows (gathered)
    const _Float16* __restrict__ xr,    // [n][HC] dest-transform rows
    const _Float16* __restrict__ erel,  // [NR rows][ldE] relations@We slice
    int ldE,
    const long long* __restrict__ adj,  // (src | rel<<32) pairs, CSR by dst
    const int* __restrict__ offsets,
    const float* __restrict__ att,      // [HC] f32
    const float* __restrict__ bias,     // CONCAT ? [HC] : [CPH]
    void* __restrict__ out, int n)
{
    constexpr int HC  = NH * CPH;
    constexpr int VPL = HC / 64;
    constexpr int NP  = VPL / 2;
    const int lane = threadIdx.x;
    const int v = blockIdx.x;
    if (v >= n) return;
    const int loff = lane * VPL;

    h2 xlv[NP], xrv[NP], attp[NP], acc[NP];
    load_h<NP>(xl + (size_t)v * HC + loff, xlv);
    load_h_nt<NP>(xr + (size_t)v * HC + loff, xrv);
    #pragma unroll
    for (int p = 0; p < NP; ++p) {
        attp[p][0] = (_Float16)att[loff + 2 * p];
        attp[p][1] = (_Float16)att[loff + 2 * p + 1];
        acc[p] = xlv[p];
    }

    // self loop logit
    float pS = 0.f;
    #pragma unroll
    for (int p = 0; p < NP; ++p) pS = fdot2a(lrelu2(xlv[p] + xrv[p]), attp[p], pS);
    pS += __shfl_xor(pS, 1);
    pS += __shfl_xor(pS, 2);
    pS += __shfl_xor(pS, 4);
    pS += __shfl_xor(pS, 8);
    float m_run = pS, l_run = 1.f;

    const int beg = offsets[v], end = offsets[v + 1];
    int idx = beg;
    for (; idx + 4 <= end; idx += 4) {
        int es[4], er[4];
        #pragma unroll
        for (int k = 0; k < 4; ++k) adj_nt(&adj[idx + k], es[k], er[k]);
        h2 xs[4][NP], ee[4][NP];
        #pragma unroll
        for (int k = 0; k < 4; ++k) {
            load_h<NP>(xl + (size_t)es[k] * HC + loff, xs[k]);
            load_h<NP>(erel + (size_t)er[k] * ldE + loff, ee[k]);
        }
        float pp[4] = {};
        #pragma unroll
        for (int p = 0; p < NP; ++p)
            #pragma unroll
            for (int k = 0; k < 4; ++k)
                pp[k] = fdot2a(lrelu2(xs[k][p] + xrv[p] + ee[k][p]), attp[p], pp[k]);
        #pragma unroll
        for (int msk = 1; msk <= 8; msk <<= 1)
            #pragma unroll
            for (int k = 0; k < 4; ++k) pp[k] += __shfl_xor(pp[k], msk);
        float mx = m_run;
        #pragma unroll
        for (int k = 0; k < 4; ++k) mx = fmaxf(mx, pp[k]);
        float sc = __expf(m_run - mx);
        float w[4], lsum = 0.f;
        #pragma unroll
        for (int k = 0; k < 4; ++k) { w[k] = __expf(pp[k] - mx); lsum += w[k]; }
        l_run = l_run * sc + lsum;
        h2 sc2 = b2(sc);
        #pragma unroll
        for (int p = 0; p < NP; ++p) {
            h2 a = acc[p] * sc2;
            #pragma unroll
            for (int k = 0; k < 4; ++k) a += xs[k][p] * b2(w[k]);
            acc[p] = a;
        }
        m_run = mx;
    }
    for (; idx < end; ++idx) {
        int es0, er0;
        adj_nt(&adj[idx], es0, er0);
        h2 xs0[NP], e0[NP];
        load_h<NP>(xl + (size_t)es0 * HC + loff, xs0);
        load_h<NP>(erel + (size_t)er0 * ldE + loff, e0);
        float p0 = 0.f;
        #pragma unroll
        for (int p = 0; p < NP; ++p)
            p0 = fdot2a(lrelu2(xs0[p] + xrv[p] + e0[p]), attp[p], p0);
        p0 += __shfl_xor(p0, 1);
        p0 += __shfl_xor(p0, 2);
        p0 += __shfl_xor(p0, 4);
        p0 += __shfl_xor(p0, 8);
        float mx = fmaxf(m_run, p0);
        float sc = __expf(m_run - mx);
        float w0 = __expf(p0 - mx);
        l_run = l_run * sc + w0;
        h2 sc2 = b2(sc), w02 = b2(w0);
        #pragma unroll
        for (int p = 0; p < NP; ++p) acc[p] = acc[p] * sc2 + xs0[p] * w02;
        m_run = mx;
    }

    float inv = 1.f / l_run;
    if constexpr (CONCAT) {
        _Float16* ob = (_Float16*)out + (size_t)v * HC + loff;
        if constexpr (NP == 2) {
            h4 o;
            #pragma unroll
            for (int p = 0; p < NP; ++p) {
                o[2 * p]     = (_Float16)((float)acc[p][0] * inv + bias[loff + 2 * p]);
                o[2 * p + 1] = (_Float16)((float)acc[p][1] * inv + bias[loff + 2 * p + 1]);
            }
            *(h4*)ob = o;
        } else {
            h8 o;
            #pragma unroll
            for (int p = 0; p < NP; ++p) {
                o[2 * p]     = (_Float16)((float)acc[p][0] * inv + bias[loff + 2 * p]);
                o[2 * p + 1] = (_Float16)((float)acc[p][1] * inv + bias[loff + 2 * p + 1]);
            }
            *(h8*)ob = o;
        }
    } else {
        float* of = (float*)out;
        float t[VPL];
        #pragma unroll
        for (int j = 0; j < VPL; ++j) {
            t[j] = (float)acc[j / 2][j & 1] * inv;
            t[j] += __shfl_xor(t[j], 16);
            t[j] += __shfl_xor(t[j], 32);
        }
        if (lane < 16) {
            #pragma unroll
            for (int j = 0; j < VPL; ++j)
                __builtin_nontemporal_store(
                    0.25f * t[j] + bias[lane * VPL + j],
                    &of[(size_t)v * CPH + lane * VPL + j]);
        }
    }
}

// ---------------- host launcher ----------------
extern "C" void kernel_launch(void* const* d_in, const int* in_sizes, int n_in,
                              void* d_out, int out_size, void* d_ws, size_t ws_size,
                              hipStream_t stream)
{
    const float* x         = (const float*)d_in[0];
    const int*   ei        = (const int*)d_in[1];
    const float* relations = (const float*)d_in[2];
    const float* Wl1  = (const float*)d_in[3];
    const float* bl1  = (const float*)d_in[4];
    const float* Wr1  = (const float*)d_in[5];
    const float* br1  = (const float*)d_in[6];
    const float* We1  = (const float*)d_in[7];
    const float* att1 = (const float*)d_in[8];
    const float* bias1= (const float*)d_in[9];
    const float* Wl2  = (const float*)d_in[10];
    const float* bl2  = (const float*)d_in[11];
    const float* Wr2  = (const float*)d_in[12];
    const float* br2  = (const float*)d_in[13];
    const float* We2  = (const float*)d_in[14];
    const float* att2 = (const float*)d_in[15];
    const float* bias2= (const float*)d_in[16];
    float* out = (float*)d_out;

    const int* src = ei;
    const int* rel = ei + NE;
    const int* dst = ei + 2 * NE;

    // ---- workspace layout (f16 = _Float16) ----
    _Float16* xh   = (_Float16*)d_ws;                  // MPAD*128
    _Float16* hh   = xh + (size_t)MPAD * 128;          // MPAD*256
    _Float16* xl1  = hh + (size_t)MPAD * 256;          // NN*256
    _Float16* xr1  = xl1 + (size_t)NN * 256;           // NN*256
    _Float16* xl2  = xr1 + (size_t)NN * 256;           // NN*512
    _Float16* xr2  = xl2 + (size_t)NN * 512;           // NN*512
    _Float16* Bt1  = xr2 + (size_t)NN * 512;           // 512*128
    _Float16* Bt2  = Bt1 + 512 * 128;                  // 1024*256
    _Float16* BtE  = Bt2 + 1024 * 256;                 // 768*128
    _Float16* relh = BtE + 768 * 128;                  // 512*128 (500 used)
    _Float16* erelC= relh + 512 * 128;                 // 512*768 (500 used)
    float* pb1     = (float*)(erelC + 512 * 768);      // 512
    float* pb2     = pb1 + 512;                        // 1024
    int* deg     = (int*)(pb2 + 1024);
    int* cursor  = deg + NN;
    int* offsets = cursor + NN;       // NN+1
    int* bsum    = offsets + NN + 1;  // 256
    int* boff    = bsum + 256;        // 256 (+pad to 8B align below)
    long long* adj = (long long*)(boff + 256 + 2);  // NE pairs (8B aligned)

    const int NB = (NN + 255) / 256;  // 196
    const int EB = (NE + 255) / 256;

    // --- zero deg+cursor (adjacent) ---
    hipMemsetAsync(deg, 0, (size_t)2 * NN * sizeof(int), stream);

    // --- one-shot prep (converts/transposes/bias packing + degree count) ---
    prep_all<<<2048, 256, 0, stream>>>(x, Wl1, Wr1, Wl2, Wr2, We1, We2, relations,
                                       bl1, br1, bl2, br2, dst, deg,
                                       xh, Bt1, Bt2, BtE, relh, pb1, pb2);

    // --- CSR by destination ---
    scan_block_sums<<<NB, 256, 0, stream>>>(deg, bsum, NN);
    scan_bsums<<<1, 256, 0, stream>>>(bsum, boff, NB);
    scan_final<<<NB, 256, 0, stream>>>(deg, boff, offsets, NN);
    fill_adj<<<EB, 256, 0, stream>>>(src, rel, dst, offsets, cursor, adj, NE);

    // --- relation tables: erelC[500 x 768] = relations @ [We1 | We2] ---
    gemm_mfma<<<4 * 6, 256, 0, stream>>>(relh, BtE, nullptr, erelC, nullptr,
                                         NR, 768, 128, 6);

    // --- layer 1 transform: xl1 = x@Wl1+bl1, xr1 = x@Wr1+br1 (one GEMM) ---
    gemm_mfma<<<(MPAD / 128) * 4, 256, 0, stream>>>(xh, Bt1, pb1, xl1, xr1,
                                                    NN, 512, 128, 4);

    // --- layer 1 attention -> h (f16); 1 wave per block ---
    gat_node<HIDC, true><<<NN, 64, 0, stream>>>(
        xl1, xr1, erelC, 768, adj, offsets, att1, bias1, hh, NN);

    // --- layer 2 transform: xl2 = h@Wl2+bl2, xr2 = h@Wr2+br2 ---
    gemm_mfma<<<(MPAD / 128) * 8, 256, 0, stream>>>(hh, Bt2, pb2, xl2, xr2,
                                                    NN, 1024, 256, 8);

    // --- layer 2 attention (mean over heads) -> out ---
    gat_node<OUTC, false><<<NN, 64, 0, stream>>>(
        xl2, xr2, erelC + 256, 768, adj, offsets, att2, bias2, out, NN);
}